// Round 10
// baseline (1464.003 us; speedup 1.0000x reference)
//
#include <hip/hip_runtime.h>
#include <hip/hip_bf16.h>

// MobiusCollapseLayer: B=4,S=2048,D=1024,P=9,M=256, 3 twists. N=8192 tokens.
// Round 10: mgemm4 = r9 buffering (256x128, 3x48KB LDS, 2-deep prefetch,
// vmcnt(6)) + per-phase interleave: 4 phases/K-tile, each {ds_read B-pair
// (+A frags in ph0) || 2 staging gloads -> barrier -> setprio MFMA-cluster
// -> barrier}. Faithful T3 port; only delta vs r9 is the interleave.
typedef unsigned short u16;
typedef short bf16x8 __attribute__((ext_vector_type(8)));
typedef float f32x4 __attribute__((ext_vector_type(4)));

constexpr int Dd = 1024, Pp = 9, Mm = 256, Nn = 8192, Kc = 2304;
constexpr float EPSf = 1e-6f;

__device__ __forceinline__ float bf2f(u16 u) {
    union { unsigned int u; float f; } v; v.u = ((unsigned int)u) << 16; return v.f;
}
__device__ __forceinline__ u16 f2bf(float f) {
    union { float f; unsigned int u; } v; v.f = f;
    unsigned int r = (v.u + 0x7FFFu + ((v.u >> 16) & 1u)) >> 16; return (u16)r;
}
__device__ __forceinline__ void split2(float v, u16& h, u16& l) {
    h = f2bf(v); l = f2bf(v - bf2f(h));
}
__device__ __forceinline__ void gld16(u16* lds, const u16* g) {
    __builtin_amdgcn_global_load_lds(
        (const __attribute__((address_space(1))) unsigned int*)g,
        (__attribute__((address_space(3))) unsigned int*)lds, 16, 0, 0);
}

// ---------------- weight prep: rotate + transpose + split ----------------
__global__ void rotcopy_k(const float* __restrict__ src, float* __restrict__ dst,
                          int R, int C, const float* __restrict__ theta, int Pb)
{
    long total = (long)Pb * R * C;
    long idx = (long)blockIdx.x * 256 + threadIdx.x;
    if (idx >= total) return;
    int c = (int)(idx % C);
    long rp = idx / C;
    int r = (int)(rp % R);
    int pb = (int)(rp / R);
    float th = theta[pb];
    const float* s = src + ((long)pb * R + r) * C;
    float v;
    if (c == 0)      v = s[0] * cosf(th) - s[1] * sinf(th);
    else if (c == 1) v = s[0] * sinf(th) + s[1] * cosf(th);
    else             v = s[c];
    dst[idx] = v;
}

__global__ void splitW1_k(const float* __restrict__ W1, const float* __restrict__ th,
                          u16* __restrict__ h, u16* __restrict__ l)
{
    int idx = blockIdx.x * 256 + threadIdx.x;
    if (idx >= 256 * 2048) return;
    int k = idx & 2047, n = idx >> 11;
    float v;
    if (n == 0)      v = W1[(long)k * 256 + 0] * cosf(th[0]) - W1[(long)k * 256 + 1] * sinf(th[0]);
    else if (n == 1) v = W1[(long)k * 256 + 0] * sinf(th[0]) + W1[(long)k * 256 + 1] * cosf(th[0]);
    else             v = W1[(long)k * 256 + n];
    u16 hh, ll; split2(v, hh, ll); h[idx] = hh; l[idx] = ll;
}

__global__ void splitTW_k(const float* __restrict__ tW, const float* __restrict__ th,
                          u16* __restrict__ h, u16* __restrict__ l)
{
    int idx = blockIdx.x * 256 + threadIdx.x;
    if (idx >= 1024 * 1024) return;
    int k = idx & 1023, n = idx >> 10;
    float v;
    if (n == 0)      v = tW[(long)k * 1024 + 0] * cosf(th[0]) - tW[(long)k * 1024 + 1] * sinf(th[0]);
    else if (n == 1) v = tW[(long)k * 1024 + 0] * sinf(th[0]) + tW[(long)k * 1024 + 1] * cosf(th[0]);
    else             v = tW[(long)k * 1024 + n];
    u16 hh, ll; split2(v, hh, ll); h[idx] = hh; l[idx] = ll;
}

__global__ void splitWa_k(const float* __restrict__ Wa, const float* __restrict__ tha,
                          u16* __restrict__ h, u16* __restrict__ l)
{
    int idx = blockIdx.x * 256 + threadIdx.x;
    if (idx >= Kc * 1024) return;
    int k = idx & 1023, n = idx >> 10;
    int p = n >> 8, m = n & 255;
    const float* s = Wa + ((long)p * 1024 + k) * 256;
    float v;
    if (m == 0)      v = s[0] * cosf(tha[p]) - s[1] * sinf(tha[p]);
    else if (m == 1) v = s[0] * sinf(tha[p]) + s[1] * cosf(tha[p]);
    else             v = s[m];
    u16 hh, ll; split2(v, hh, ll); h[idx] = hh; l[idx] = ll;
}

__global__ void splitWb_k(const float* __restrict__ Wb, const float* __restrict__ thb,
                          u16* __restrict__ h, u16* __restrict__ l)
{
    int idx = blockIdx.x * 256 + threadIdx.x;
    if (idx >= 1024 * Kc) return;
    int n = idx / Kc;              // d
    int k = idx - n * Kc;          // p*256+m
    int p = k >> 8, m = k & 255;
    const float* s = Wb + ((long)p * 256 + m) * 1024;
    float v;
    if (n == 0)      v = s[0] * cosf(thb[p]) - s[1] * sinf(thb[p]);
    else if (n == 1) v = s[0] * sinf(thb[p]) + s[1] * cosf(thb[p]);
    else             v = s[n];
    u16 hh, ll; split2(v, hh, ll); h[idx] = hh; l[idx] = ll;
}

// ---------------- neighbor mixer -> split bf16 ----------------
__global__ void mixer_k(const float* __restrict__ x, const float* __restrict__ mw,
                        u16* __restrict__ xmh, u16* __restrict__ xml)
{
    int idx = blockIdx.x * 256 + threadIdx.x;       // float4 index, total N*D/4
    if (idx >= Nn * Dd / 4) return;
    int d4 = idx & (Dd / 4 - 1);
    int n = idx >> 8;
    int s = n & 2047;                               // S=2048
    const float4* x4 = (const float4*)x;
    const float4* w4 = (const float4*)mw;
    float4 xc = x4[idx];
    float4 w0 = w4[d4], w1 = w4[(Dd / 4) + d4], w2 = w4[2 * (Dd / 4) + d4];
    float o[4];
    o[0] = xc.x * w0.x; o[1] = xc.y * w0.y; o[2] = xc.z * w0.z; o[3] = xc.w * w0.w;
    if (s > 0) {
        float4 xl = x4[idx - Dd / 4];
        o[0] += xl.x * w1.x; o[1] += xl.y * w1.y; o[2] += xl.z * w1.z; o[3] += xl.w * w1.w;
    }
    if (s < 2047) {
        float4 xr = x4[idx + Dd / 4];
        o[0] += xr.x * w2.x; o[1] += xr.y * w2.y; o[2] += xr.z * w2.z; o[3] += xr.w * w2.w;
    }
    ushort4 h4, l4;
    split2(o[0], h4.x, l4.x); split2(o[1], h4.y, l4.y);
    split2(o[2], h4.z, l4.z); split2(o[3], h4.w, l4.w);
    ((ushort4*)xmh)[idx] = h4; ((ushort4*)xml)[idx] = l4;
}

__global__ void tanh_k(const float* __restrict__ a, float* __restrict__ o, int total)
{
    int idx = blockIdx.x * 256 + threadIdx.x;
    if (idx < total) o[idx] = tanhf(a[idx]);
}

// tin = recompose(xm) + tbr  -> split  (t=0 path; runs AFTER logits reads hbuf)
__global__ void addb_split_k(const u16* __restrict__ xmh, const u16* __restrict__ xml,
                             const float* __restrict__ tbr,
                             u16* __restrict__ th_, u16* __restrict__ tl_)
{
    int idx = blockIdx.x * 256 + threadIdx.x;   // ushort4 index over N*D/4
    if (idx >= Nn * Dd / 4) return;
    int d4 = idx & (Dd / 4 - 1);
    ushort4 xh = ((const ushort4*)xmh)[idx], xl = ((const ushort4*)xml)[idx];
    float4 b = ((const float4*)tbr)[d4];
    ushort4 h4, l4;
    split2(bf2f(xh.x) + bf2f(xl.x) + b.x, h4.x, l4.x);
    split2(bf2f(xh.y) + bf2f(xl.y) + b.y, h4.y, l4.y);
    split2(bf2f(xh.z) + bf2f(xl.z) + b.z, h4.z, l4.z);
    split2(bf2f(xh.w) + bf2f(xl.w) + b.w, h4.w, l4.w);
    ((ushort4*)th_)[idx] = h4; ((ushort4*)tl_)[idx] = l4;
}

// ============ r5 kernel (128x128, 4 waves) — kept for EPI 0,1,4 ============
template<int EPI>
__global__ __launch_bounds__(256, 2) void mgemm(
    const u16* __restrict__ Agh, const u16* __restrict__ Agl, int lda,
    const u16* __restrict__ Bgh, const u16* __restrict__ Bgl, int ldb,
    int K,
    float* __restrict__ Cf, int ldc,
    const float* __restrict__ Cinit,
    const float* __restrict__ bias,
    const float* __restrict__ rwv,
    const float* __restrict__ rwv2,
    const float* __restrict__ bbrv)
{
    __shared__ u16 smem[2][16384];
    const int tid = threadIdx.x, wave = tid >> 6, lane = tid & 63;
    const int nwg = gridDim.x * gridDim.y;
    const int flat = blockIdx.y * gridDim.x + blockIdx.x;
    const int q = nwg >> 3;
    const int l_ = (flat & 7) * q + (flat >> 3);
    const int r0 = (l_ / gridDim.x) * 128, c0 = (l_ % gridDim.x) * 128;
    const int srl = lane >> 2;
    const int ssl = ((lane & 3) ^ ((lane >> 3) & 3)) * 8;
    const int frl = lane & 15, kh = lane >> 4;
    const int sw  = (kh ^ ((frl >> 1) & 3)) * 8;
    const int arow0 = (wave >> 1) * 64, bcol0 = (wave & 1) * 64;
    const int w32 = wave * 32;

    f32x4 acc[4][4] = {};
    f32x4 acc2[4][4];
    if constexpr (EPI == 4) {
#pragma unroll
        for (int i = 0; i < 4; ++i)
#pragma unroll
            for (int j = 0; j < 4; ++j) acc2[i][j] = f32x4{0.f, 0.f, 0.f, 0.f};
    }

    auto STAGE = [&](int buf, int k0) {
        u16* base = &smem[buf][0];
        u16* As_h = base;        u16* As_l = base + 4096;
        u16* Bs_h = base + 8192; u16* Bs_l = base + 12288;
        const long ga0 = (long)(r0 + w32 + srl) * lda + k0 + ssl;
        gld16(&As_h[w32 * 32],        Agh + ga0);
        gld16(&As_h[(w32 + 16) * 32], Agh + ga0 + 16L * lda);
        gld16(&As_l[w32 * 32],        Agl + ga0);
        gld16(&As_l[(w32 + 16) * 32], Agl + ga0 + 16L * lda);
        const long gb0 = (long)(c0 + w32 + srl) * ldb + k0 + ssl;
        gld16(&Bs_h[w32 * 32],        Bgh + gb0);
        gld16(&Bs_h[(w32 + 16) * 32], Bgh + gb0 + 16L * ldb);
        gld16(&Bs_l[w32 * 32],        Bgl + gb0);
        gld16(&Bs_l[(w32 + 16) * 32], Bgl + gb0 + 16L * ldb);
    };
    auto COMPUTE = [&](int buf, f32x4 (&ac)[4][4]) {
        u16* base = &smem[buf][0];
        u16* As_h = base;        u16* As_l = base + 4096;
        u16* Bs_h = base + 8192; u16* Bs_l = base + 12288;
        bf16x8 ah[4], al[4];
#pragma unroll
        for (int f = 0; f < 4; ++f) {
            int ao = (arow0 + f * 16 + frl) * 32 + sw;
            ah[f] = *(const bf16x8*)&As_h[ao];
            al[f] = *(const bf16x8*)&As_l[ao];
        }
#pragma unroll
        for (int j = 0; j < 4; ++j) {
            int bo = (bcol0 + j * 16 + frl) * 32 + sw;
            bf16x8 bh = *(const bf16x8*)&Bs_h[bo];
            bf16x8 bl = *(const bf16x8*)&Bs_l[bo];
#pragma unroll
            for (int i = 0; i < 4; ++i) {
                ac[i][j] = __builtin_amdgcn_mfma_f32_16x16x32_bf16(ah[i], bh, ac[i][j], 0, 0, 0);
                ac[i][j] = __builtin_amdgcn_mfma_f32_16x16x32_bf16(ah[i], bl, ac[i][j], 0, 0, 0);
                ac[i][j] = __builtin_amdgcn_mfma_f32_16x16x32_bf16(al[i], bh, ac[i][j], 0, 0, 0);
            }
        }
    };
    auto FLUSH = [&](int p) {
#pragma unroll
        for (int i = 0; i < 4; ++i)
#pragma unroll
            for (int reg = 0; reg < 4; ++reg) {
                float w = rwv[(long)(r0 + arow0 + i * 16 + kh * 4 + reg) * 9 + p];
#pragma unroll
                for (int j = 0; j < 4; ++j) {
                    acc[i][j][reg] += w * acc2[i][j][reg];
                    acc2[i][j][reg] = 0.f;
                }
            }
    };

    const int NT = K / 32;
    STAGE(0, 0);
#pragma unroll 1
    for (int t = 0; t < NT; t += 2) {
        STAGE(1, (t + 1) * 32);
        asm volatile("s_waitcnt vmcnt(8)" ::: "memory");
        __builtin_amdgcn_sched_barrier(0);
        __builtin_amdgcn_s_barrier();
        __builtin_amdgcn_sched_barrier(0);
        if constexpr (EPI == 4) COMPUTE(0, acc2); else COMPUTE(0, acc);
        __builtin_amdgcn_sched_barrier(0);
        __builtin_amdgcn_s_barrier();
        __builtin_amdgcn_sched_barrier(0);
        if (t + 2 < NT) {
            STAGE(0, (t + 2) * 32);
            asm volatile("s_waitcnt vmcnt(8)" ::: "memory");
        } else {
            asm volatile("s_waitcnt vmcnt(0)" ::: "memory");
        }
        __builtin_amdgcn_sched_barrier(0);
        __builtin_amdgcn_s_barrier();
        __builtin_amdgcn_sched_barrier(0);
        if constexpr (EPI == 4) COMPUTE(1, acc2); else COMPUTE(1, acc);
        __builtin_amdgcn_sched_barrier(0);
        __builtin_amdgcn_s_barrier();
        __builtin_amdgcn_sched_barrier(0);
        if constexpr (EPI == 4) {
            if (((t + 1) & 7) == 7) FLUSH((t + 1) >> 3);
        }
    }

#pragma unroll
    for (int i = 0; i < 4; ++i)
#pragma unroll
        for (int reg = 0; reg < 4; ++reg) {
            const int r = r0 + arow0 + i * 16 + kh * 4 + reg;
#pragma unroll
            for (int j = 0; j < 4; ++j) {
                const int c = c0 + bcol0 + j * 16 + frl;
                float v = acc[i][j][reg];
                if constexpr (EPI == 0) {
                    Cf[(long)r * ldc + c] = v + bias[c];
                } else if constexpr (EPI == 1) {
                    Cf[(long)r * ldc + c] = tanhf(v + Cinit[(long)r * ldc + c]);
                } else if constexpr (EPI == 4) {
#pragma unroll
                    for (int p = 0; p < 9; ++p) v += rwv2[(long)r * 9 + p] * bbrv[p * 1024 + c];
                    Cf[(long)r * ldc + c] = v;
                }
            }
        }
}

// == mgemm4: 256x128, 8 waves, 3x48KB LDS, 2-deep prefetch + 4-phase interleave ==
// EPI 2: acc + CIsplit + bias -> split out  (twist)
// EPI 3: (acc + bias) * rw[r][c>>8] -> split out  (stage A)
// EPI 5: acc + sum_p rwv*bbr -> f32         (stage B)
template<int EPI>
__global__ __launch_bounds__(512, 2) void mgemm4(
    const u16* __restrict__ Agh, const u16* __restrict__ Agl, int lda,
    const u16* __restrict__ Bgh, const u16* __restrict__ Bgl, int ldb,
    int K,
    float* __restrict__ Cf, u16* __restrict__ Coh, u16* __restrict__ Col, int ldc,
    const u16* __restrict__ CIh, const u16* __restrict__ CIl,
    const float* __restrict__ bias,
    const float* __restrict__ rwv,
    const float* __restrict__ bbrv)
{
    // 3 buffers x 48KB: per buf Ah[256x32] Al[256x32] Bh[128x32] Bl[128x32]
    __shared__ u16 smem[3 * 24576];             // 144KB
    const int tid = threadIdx.x, wave = tid >> 6, lane = tid & 63;
    const int nwg = gridDim.x * gridDim.y;
    const int flat = blockIdx.y * gridDim.x + blockIdx.x;
    const int q = nwg >> 3;
    const int l_ = (flat & 7) * q + (flat >> 3);
    const int r0 = (l_ / gridDim.x) * 256, c0 = (l_ % gridDim.x) * 128;
    const int srl = lane >> 2;
    const int ssl = ((lane & 3) ^ ((lane >> 3) & 3)) * 8;
    const int frl = lane & 15, kh = lane >> 4;
    const int sw  = (kh ^ ((frl >> 1) & 3)) * 8;
    const int arow0 = (wave >> 1) * 64, bcol0 = (wave & 1) * 64;   // 4x2 wave grid
    const int w32 = wave * 32, w16 = wave * 16;
    const int NT = K / 32;                      // 32 or 72

    f32x4 acc[4][4] = {};

    auto STAGE_AH = [&](u16* base, int k0) {
        const long ga = (long)(r0 + w32 + srl) * lda + k0 + ssl;
        gld16(&base[w32 * 32],        Agh + ga);
        gld16(&base[(w32 + 16) * 32], Agh + ga + 16L * lda);
    };
    auto STAGE_AL = [&](u16* base, int k0) {
        u16* Asl = base + 8192;
        const long ga = (long)(r0 + w32 + srl) * lda + k0 + ssl;
        gld16(&Asl[w32 * 32],        Agl + ga);
        gld16(&Asl[(w32 + 16) * 32], Agl + ga + 16L * lda);
    };
    auto STAGE_B = [&](u16* base, int k0) {
        u16* Bsh = base + 16384;
        u16* Bsl = base + 20480;
        const long gb = (long)(c0 + w16 + srl) * ldb + k0 + ssl;
        gld16(&Bsh[w16 * 32], Bgh + gb);
        gld16(&Bsl[w16 * 32], Bgl + gb);
    };

    u16* b0 = smem;
    u16* b1 = smem + 24576;
    u16* b2 = smem + 49152;
    // prologue: 2 tiles in flight (12 loads/thread)
    STAGE_AH(b0, 0);  STAGE_AL(b0, 0);  STAGE_B(b0, 0);
    STAGE_AH(b1, 32); STAGE_AL(b1, 32); STAGE_B(b1, 32);

#pragma unroll 1
    for (int t = 0; t < NT; ++t) {
        // top-of-tile: tile t's 6 loads landed; tile t+1's stay in flight
        if (t + 1 < NT) asm volatile("s_waitcnt vmcnt(6)" ::: "memory");
        else            asm volatile("s_waitcnt vmcnt(0)" ::: "memory");
        __builtin_amdgcn_sched_barrier(0);
        __builtin_amdgcn_s_barrier();
        __builtin_amdgcn_sched_barrier(0);

        const u16* Ash = b0;
        const u16* Asl = b0 + 8192;
        const u16* Bsh = b0 + 16384;
        const u16* Bsl = b0 + 20480;
        const bool pf = (t + 2 < NT);
        const int kpf = (t + 2) * 32;
        bf16x8 ah[4], al[4];

        // ---- 4 phases: {ds_read || gload-issue} BAR {setprio 12xMFMA} BAR
#pragma unroll
        for (int j = 0; j < 4; ++j) {
            if (j == 0) {
#pragma unroll
                for (int f = 0; f < 4; ++f) {
                    int ao = (arow0 + f * 16 + frl) * 32 + sw;
                    ah[f] = *(const bf16x8*)&Ash[ao];
                    al[f] = *(const bf16x8*)&Asl[ao];
                }
            }
            int bo = (bcol0 + j * 16 + frl) * 32 + sw;
            bf16x8 bh = *(const bf16x8*)&Bsh[bo];
            bf16x8 bl = *(const bf16x8*)&Bsl[bo];
            if (pf) {
                if (j == 0)      STAGE_AH(b2, kpf);
                else if (j == 1) STAGE_AL(b2, kpf);
                else if (j == 2) STAGE_B(b2, kpf);
            }
            __builtin_amdgcn_sched_barrier(0);
            __builtin_amdgcn_s_barrier();
            __builtin_amdgcn_sched_barrier(0);
            __builtin_amdgcn_s_setprio(1);
#pragma unroll
            for (int i = 0; i < 4; ++i) {
                acc[i][j] = __builtin_amdgcn_mfma_f32_16x16x32_bf16(ah[i], bh, acc[i][j], 0, 0, 0);
                acc[i][j] = __builtin_amdgcn_mfma_f32_16x16x32_bf16(ah[i], bl, acc[i][j], 0, 0, 0);
                acc[i][j] = __builtin_amdgcn_mfma_f32_16x16x32_bf16(al[i], bh, acc[i][j], 0, 0, 0);
            }
            __builtin_amdgcn_s_setprio(0);
            __builtin_amdgcn_sched_barrier(0);
            __builtin_amdgcn_s_barrier();
            __builtin_amdgcn_sched_barrier(0);
        }
        u16* tp = b0; b0 = b1; b1 = b2; b2 = tp;
    }
    __builtin_amdgcn_sched_barrier(0);

#pragma unroll
    for (int i = 0; i < 4; ++i)
#pragma unroll
        for (int reg = 0; reg < 4; ++reg) {
            const int r = r0 + arow0 + i * 16 + kh * 4 + reg;
#pragma unroll
            for (int j = 0; j < 4; ++j) {
                const int c = c0 + bcol0 + j * 16 + frl;
                float v = acc[i][j][reg];
                if constexpr (EPI == 2) {
                    long o = (long)r * ldc + c;
                    v += bf2f(CIh[o]) + bf2f(CIl[o]) + bias[c];
                    u16 h, l; split2(v, h, l); Coh[o] = h; Col[o] = l;
                } else if constexpr (EPI == 3) {
                    long o = (long)r * ldc + c;
                    v = (v + bias[c]) * rwv[(long)r * 9 + (c >> 8)];
                    u16 h, l; split2(v, h, l); Coh[o] = h; Col[o] = l;
                } else {            // EPI 5
#pragma unroll
                    for (int p = 0; p < 9; ++p) v += rwv[(long)r * 9 + p] * bbrv[p * 1024 + c];
                    Cf[(long)r * ldc + c] = v;
                }
            }
        }
}

// ---------------- logits + softmax / hard ----------------
__global__ void logits_k(const float* __restrict__ h, const float* __restrict__ W2r,
                         const float* __restrict__ b2r, const float* __restrict__ gum,
                         float* __restrict__ rwA, float* __restrict__ rwH,
                         const float* __restrict__ rwS, int hard)
{
    __shared__ float hs[Mm];
    __shared__ float lg[16];
    int n = blockIdx.x;
    for (int i = threadIdx.x; i < Mm; i += 64) hs[i] = h[(long)n * Mm + i];
    __syncthreads();
    if (threadIdx.x < Pp) {
        int p = threadIdx.x;
        float acc = b2r[p];
        for (int m = 0; m < Mm; ++m) acc += hs[m] * W2r[m * Pp + p];
        lg[p] = acc + gum[(long)n * Pp + p];
    }
    __syncthreads();
    if (threadIdx.x == 0) {
        float mx = lg[0]; int am = 0;
#pragma unroll
        for (int p = 1; p < Pp; ++p) if (lg[p] > mx) { mx = lg[p]; am = p; }
        if (hard) {
#pragma unroll
            for (int p = 0; p < Pp; ++p) {
                rwA[(long)n * Pp + p] = (p == am) ? 1.f / rwS[(long)n * Pp + p] : 0.f;
                rwH[(long)n * Pp + p] = (p == am) ? 1.f : 0.f;
            }
        } else {
            float e[Pp]; float ssum = 0.f;
#pragma unroll
            for (int p = 0; p < Pp; ++p) { e[p] = expf(lg[p] - mx); ssum += e[p]; }
#pragma unroll
            for (int p = 0; p < Pp; ++p) rwA[(long)n * Pp + p] = e[p] / ssum;
        }
    }
}

// ---------------- mod-phase RMS norm (group = d % 7) ----------------
template<int INSPLIT, int OUTSPLIT>
__global__ void norm_k(const float* __restrict__ in,
                       const u16* __restrict__ inh, const u16* __restrict__ inl,
                       const float* __restrict__ add, const float* __restrict__ g,
                       float* __restrict__ outf, u16* __restrict__ oh, u16* __restrict__ ol)
{
    __shared__ float sb[256][8];
    __shared__ float dn[8];
    int n = blockIdx.x;
    int t = threadIdx.x;
    float v[4];
#pragma unroll
    for (int j = 0; j < 7; ++j) sb[t][j] = 0.f;
#pragma unroll
    for (int i = 0; i < 4; ++i) {
        int d = t + i * 256;
        long o = (long)n * Dd + d;
        float xv = INSPLIT ? (bf2f(inh[o]) + bf2f(inl[o])) : in[o];
        if (add) xv += add[o];
        v[i] = xv;
        sb[t][d % 7] += xv * xv;
    }
    __syncthreads();
    for (int st = 128; st >= 1; st >>= 1) {
        if (t < st) {
#pragma unroll
            for (int j = 0; j < 7; ++j) sb[t][j] += sb[t + st][j];
        }
        __syncthreads();
    }
    if (t < 7) {
        const float cnt = (t < 2) ? 147.f : 146.f;
        dn[t] = 1.f / sqrtf(sb[0][t] / cnt + EPSf);
    }
    __syncthreads();
#pragma unroll
    for (int i = 0; i < 4; ++i) {
        int d = t + i * 256;
        long o = (long)n * Dd + d;
        float ov = v[i] * dn[d % 7] * g[d];
        if (OUTSPLIT) { u16 h, l; split2(ov, h, l); oh[o] = h; ol[o] = l; }
        else outf[o] = ov;
    }
}

static inline int cdiv(long a, long b) { return (int)((a + b - 1) / b); }

extern "C" void kernel_launch(void* const* d_in, const int* in_sizes, int n_in,
                              void* d_out, int out_size, void* d_ws, size_t ws_size,
                              hipStream_t stream)
{
    const float* x    = (const float*)d_in[0];
    const float* gum  = (const float*)d_in[1];
    const float* mw   = (const float*)d_in[2];
    const float* W1   = (const float*)d_in[3];
    const float* b1   = (const float*)d_in[4];
    const float* th1  = (const float*)d_in[5];
    const float* W2   = (const float*)d_in[6];
    const float* b2   = (const float*)d_in[7];
    const float* th2  = (const float*)d_in[8];
    const float* Wa   = (const float*)d_in[9];
    const float* ba   = (const float*)d_in[10];
    const float* tha  = (const float*)d_in[11];
    const float* Wb   = (const float*)d_in[12];
    const float* bbv  = (const float*)d_in[13];
    const float* thb  = (const float*)d_in[14];
    const float* tW   = (const float*)d_in[15];
    const float* tb   = (const float*)d_in[16];
    const float* tth  = (const float*)d_in[17];
    const float* gnorm = (const float*)d_in[18];

    char* cur = (char*)d_ws;
    auto alloc = [&](size_t bytes) -> void* {
        void* r = (void*)cur; cur += (bytes + 255) & ~(size_t)255; return r;
    };
    void* region = alloc((size_t)Nn * Dd * 4);   // craw f32 == {tinh|tinl} == hbuf f32
    float* craw = (float*)region;
    float* hbuf = (float*)region;
    u16*   tinh = (u16*)region;
    u16*   tinl = tinh + (size_t)Nn * Dd;
    float* zx   = (float*)alloc((size_t)Nn * Mm * 4);
    float* rwS  = (float*)alloc((size_t)Nn * Pp * 4);
    float* rwD  = (float*)alloc((size_t)Nn * Pp * 4);
    float* rwH  = (float*)alloc((size_t)Nn * Pp * 4);
    u16* xmh  = (u16*)alloc((size_t)Nn * Dd * 2);
    u16* xml  = (u16*)alloc((size_t)Nn * Dd * 2);
    u16* colh = (u16*)alloc((size_t)Nn * Dd * 2);
    u16* coll = (u16*)alloc((size_t)Nn * Dd * 2);
    u16* hph  = (u16*)alloc((size_t)Nn * Kc * 2);
    u16* hpl  = (u16*)alloc((size_t)Nn * Kc * 2);
    u16* W1th = (u16*)alloc(256 * 2048 * 2);
    u16* W1tl = (u16*)alloc(256 * 2048 * 2);
    u16* tWth = (u16*)alloc(1024 * 1024 * 2);
    u16* tWtl = (u16*)alloc(1024 * 1024 * 2);
    u16* Wath = (u16*)alloc((size_t)Kc * 1024 * 2);
    u16* Watl = (u16*)alloc((size_t)Kc * 1024 * 2);
    u16* Wbth = (u16*)alloc((size_t)1024 * Kc * 2);
    u16* Wbtl = (u16*)alloc((size_t)1024 * Kc * 2);
    float* W2r = (float*)alloc(256 * 9 * 4);
    float* b1r = (float*)alloc(256 * 4);
    float* b2r = (float*)alloc(16 * 4);
    float* bac = (float*)alloc(Kc * 4);
    float* bbr = (float*)alloc(Pp * 1024 * 4);
    float* tbr = (float*)alloc(1024 * 4);
    if ((size_t)(cur - (char*)d_ws) > ws_size) return;

    float* out0 = (float*)d_out;
    float* out1 = out0 + (long)Nn * Dd;

    // ---- prep ----
    splitW1_k<<<2048, 256, 0, stream>>>(W1, th1, W1th, W1tl);
    splitTW_k<<<4096, 256, 0, stream>>>(tW, tth, tWth, tWtl);
    splitWa_k<<<cdiv((long)Kc * 1024, 256), 256, 0, stream>>>(Wa, tha, Wath, Watl);
    splitWb_k<<<cdiv((long)1024 * Kc, 256), 256, 0, stream>>>(Wb, thb, Wbth, Wbtl);
    rotcopy_k<<<cdiv(256L * 9, 256), 256, 0, stream>>>(W2, W2r, 256, 9, th2, 1);
    rotcopy_k<<<1, 256, 0, stream>>>(b1, b1r, 1, 256, th1, 1);
    rotcopy_k<<<1, 256, 0, stream>>>(b2, b2r, 1, 9, th2, 1);
    rotcopy_k<<<cdiv((long)Pp * Mm, 256), 256, 0, stream>>>(ba, bac, 1, 256, tha, 9);
    rotcopy_k<<<cdiv((long)Pp * 1024, 256), 256, 0, stream>>>(bbv, bbr, 1, 1024, thb, 9);
    rotcopy_k<<<cdiv(1024L, 256), 256, 0, stream>>>(tb, tbr, 1, 1024, tth, 1);

    // ---- x_mixed (split) ----
    mixer_k<<<Nn * Dd / 4 / 256, 256, 0, stream>>>(x, mw, xmh, xml);

    // ---- zx = x_mixed @ W1_top + b1r ----
    mgemm<0><<<dim3(2, 64), 256, 0, stream>>>(
        xmh, xml, 1024, W1th, W1tl, 2048, 1024,
        zx, 256, nullptr, b1r, nullptr, nullptr, nullptr);

    for (int t = 0; t < 3; ++t) {
        if (t == 0) {
            tanh_k<<<cdiv((long)Nn * Mm, 256), 256, 0, stream>>>(zx, hbuf, Nn * Mm);
        } else {
            mgemm<1><<<dim3(2, 64), 256, 0, stream>>>(
                colh, coll, 1024, W1th + 1024, W1tl + 1024, 2048, 1024,
                hbuf, 256, zx, nullptr, nullptr, nullptr, nullptr);
        }
        logits_k<<<Nn, 64, 0, stream>>>(hbuf, W2r, b2r, gum + (long)t * Nn * Pp,
                                        rwS, nullptr, nullptr, 0);
        if (t == 0) {
            // t=0 tin: AFTER logits consumed hbuf (tin aliases hbuf region!)
            addb_split_k<<<Nn * Dd / 4 / 256, 256, 0, stream>>>(xmh, xml, tbr, tinh, tinl);
        } else {
            mgemm4<2><<<dim3(8, 32), 512, 0, stream>>>(
                colh, coll, 1024, tWth, tWtl, 1024, 1024,
                nullptr, tinh, tinl, 1024, xmh, xml, tbr, nullptr, nullptr);
        }
        // stage A: hp = (tin @ Wat + bac) * rw
        mgemm4<3><<<dim3(18, 32), 512, 0, stream>>>(
            tinh, tinl, 1024, Wath, Watl, 1024, 1024,
            nullptr, hph, hpl, Kc, nullptr, nullptr, bac, rwS, nullptr);
        // stage B: craw = hp @ Wbt + sum_p rw_p bbr_p
        mgemm4<5><<<dim3(8, 32), 512, 0, stream>>>(
            hph, hpl, Kc, Wbth, Wbtl, Kc, Kc,
            craw, nullptr, nullptr, 1024, nullptr, nullptr, nullptr, rwS, bbr);
        // collapsed = mod_phase_norm(craw) -> split
        norm_k<0, 1><<<Nn, 256, 0, stream>>>(craw, nullptr, nullptr, nullptr, gnorm,
                                             nullptr, colh, coll);
    }

    // ---- final hard routing (rwS still holds t=2 soft weights) ----
    mgemm<1><<<dim3(2, 64), 256, 0, stream>>>(
        colh, coll, 1024, W1th + 1024, W1tl + 1024, 2048, 1024,
        hbuf, 256, zx, nullptr, nullptr, nullptr, nullptr);
    logits_k<<<Nn, 64, 0, stream>>>(hbuf, W2r, b2r, gum + 3L * Nn * Pp,
                                    rwD, rwH, rwS, 1);
    // fc_raw = sum_p (rw_hard/rw_soft2)_p (hp_p @ Wbt_p) + sum_p rw_hard_p bbr_p
    mgemm<4><<<dim3(8, 64), 256, 0, stream>>>(
        hph, hpl, Kc, Wbth, Wbtl, Kc, Kc,
        craw, 1024, nullptr, nullptr, rwD, rwH, bbr);
    // out0 = norm(x + fc_raw); out1 = norm(collapsed)
    norm_k<0, 0><<<Nn, 256, 0, stream>>>(craw, nullptr, nullptr, x, gnorm, out0, nullptr, nullptr);
    norm_k<1, 0><<<Nn, 256, 0, stream>>>(nullptr, colh, coll, nullptr, gnorm, out1, nullptr, nullptr);
}

// Round 11
// 1409.886 us; speedup vs baseline: 1.0384x; 1.0384x over previous
//
#include <hip/hip_runtime.h>
#include <hip/hip_bf16.h>

// MobiusCollapseLayer: B=4,S=2048,D=1024,P=9,M=256, 3 twists. N=8192 tokens.
// Round 11: algebraic twist-fold. Wfat = rot(tW) @ Wat precomputed; zxa =
// (xm+tbr)@Wat+bac precomputed; hp_t = (zxa + col@Wfat)*rw. Kills both twist
// GEMMs, addb_split, and turns t=0 stage A into an elementwise pass.
// Needs +89MB workspace -> runtime check with fallback to the proven r5 flow.
typedef unsigned short u16;
typedef short bf16x8 __attribute__((ext_vector_type(8)));
typedef float f32x4 __attribute__((ext_vector_type(4)));

constexpr int Dd = 1024, Pp = 9, Mm = 256, Nn = 8192, Kc = 2304;
constexpr float EPSf = 1e-6f;

__device__ __forceinline__ float bf2f(u16 u) {
    union { unsigned int u; float f; } v; v.u = ((unsigned int)u) << 16; return v.f;
}
__device__ __forceinline__ u16 f2bf(float f) {
    union { float f; unsigned int u; } v; v.f = f;
    unsigned int r = (v.u + 0x7FFFu + ((v.u >> 16) & 1u)) >> 16; return (u16)r;
}
__device__ __forceinline__ void split2(float v, u16& h, u16& l) {
    h = f2bf(v); l = f2bf(v - bf2f(h));
}
__device__ __forceinline__ void gld16(u16* lds, const u16* g) {
    __builtin_amdgcn_global_load_lds(
        (const __attribute__((address_space(1))) unsigned int*)g,
        (__attribute__((address_space(3))) unsigned int*)lds, 16, 0, 0);
}

// ---------------- weight prep: rotate + transpose + split ----------------
__global__ void rotcopy_k(const float* __restrict__ src, float* __restrict__ dst,
                          int R, int C, const float* __restrict__ theta, int Pb)
{
    long total = (long)Pb * R * C;
    long idx = (long)blockIdx.x * 256 + threadIdx.x;
    if (idx >= total) return;
    int c = (int)(idx % C);
    long rp = idx / C;
    int r = (int)(rp % R);
    int pb = (int)(rp / R);
    float th = theta[pb];
    const float* s = src + ((long)pb * R + r) * C;
    float v;
    if (c == 0)      v = s[0] * cosf(th) - s[1] * sinf(th);
    else if (c == 1) v = s[0] * sinf(th) + s[1] * cosf(th);
    else             v = s[c];
    dst[idx] = v;
}

__global__ void splitW1_k(const float* __restrict__ W1, const float* __restrict__ th,
                          u16* __restrict__ h, u16* __restrict__ l)
{
    int idx = blockIdx.x * 256 + threadIdx.x;
    if (idx >= 256 * 2048) return;
    int k = idx & 2047, n = idx >> 11;
    float v;
    if (n == 0)      v = W1[(long)k * 256 + 0] * cosf(th[0]) - W1[(long)k * 256 + 1] * sinf(th[0]);
    else if (n == 1) v = W1[(long)k * 256 + 0] * sinf(th[0]) + W1[(long)k * 256 + 1] * cosf(th[0]);
    else             v = W1[(long)k * 256 + n];
    u16 hh, ll; split2(v, hh, ll); h[idx] = hh; l[idx] = ll;
}

// tWt [d][e] = rot_d(tW[e][d])   (old twist-GEMM B operand; fallback only)
__global__ void splitTW_k(const float* __restrict__ tW, const float* __restrict__ th,
                          u16* __restrict__ h, u16* __restrict__ l)
{
    int idx = blockIdx.x * 256 + threadIdx.x;
    if (idx >= 1024 * 1024) return;
    int k = idx & 1023, n = idx >> 10;
    float v;
    if (n == 0)      v = tW[(long)k * 1024 + 0] * cosf(th[0]) - tW[(long)k * 1024 + 1] * sinf(th[0]);
    else if (n == 1) v = tW[(long)k * 1024 + 0] * sinf(th[0]) + tW[(long)k * 1024 + 1] * cosf(th[0]);
    else             v = tW[(long)k * 1024 + n];
    u16 hh, ll; split2(v, hh, ll); h[idx] = hh; l[idx] = ll;
}

// tWtT [e][d] = rot_d(tW[e][d])  (transposed; B operand for Wfat compute)
__global__ void splitTWT_k(const float* __restrict__ tW, const float* __restrict__ th,
                           u16* __restrict__ h, u16* __restrict__ l)
{
    int idx = blockIdx.x * 256 + threadIdx.x;
    if (idx >= 1024 * 1024) return;
    int d = idx & 1023, e = idx >> 10;
    const float* s = tW + (long)e * 1024;
    float v;
    if (d == 0)      v = s[0] * cosf(th[0]) - s[1] * sinf(th[0]);
    else if (d == 1) v = s[0] * sinf(th[0]) + s[1] * cosf(th[0]);
    else             v = s[d];
    u16 hh, ll; split2(v, hh, ll); h[idx] = hh; l[idx] = ll;
}

__global__ void splitWa_k(const float* __restrict__ Wa, const float* __restrict__ tha,
                          u16* __restrict__ h, u16* __restrict__ l)
{
    int idx = blockIdx.x * 256 + threadIdx.x;
    if (idx >= Kc * 1024) return;
    int k = idx & 1023, n = idx >> 10;
    int p = n >> 8, m = n & 255;
    const float* s = Wa + ((long)p * 1024 + k) * 256;
    float v;
    if (m == 0)      v = s[0] * cosf(tha[p]) - s[1] * sinf(tha[p]);
    else if (m == 1) v = s[0] * sinf(tha[p]) + s[1] * cosf(tha[p]);
    else             v = s[m];
    u16 hh, ll; split2(v, hh, ll); h[idx] = hh; l[idx] = ll;
}

__global__ void splitWb_k(const float* __restrict__ Wb, const float* __restrict__ thb,
                          u16* __restrict__ h, u16* __restrict__ l)
{
    int idx = blockIdx.x * 256 + threadIdx.x;
    if (idx >= 1024 * Kc) return;
    int n = idx / Kc;              // d
    int k = idx - n * Kc;          // p*256+m
    int p = k >> 8, m = k & 255;
    const float* s = Wb + ((long)p * 256 + m) * 1024;
    float v;
    if (n == 0)      v = s[0] * cosf(thb[p]) - s[1] * sinf(thb[p]);
    else if (n == 1) v = s[0] * sinf(thb[p]) + s[1] * cosf(thb[p]);
    else             v = s[n];
    u16 hh, ll; split2(v, hh, ll); h[idx] = hh; l[idx] = ll;
}

// bac2[pm] = bac[pm] + sum_d tbr[d] * Wat[pm,d]
__global__ void bac2_k(const float* __restrict__ bac, const float* __restrict__ tbr,
                       const u16* __restrict__ Wath, const u16* __restrict__ Watl,
                       float* __restrict__ bac2)
{
    __shared__ float sb[256];
    int pm = blockIdx.x;
    int t = threadIdx.x;
    float s = 0.f;
    for (int d = t; d < 1024; d += 256) {
        long o = (long)pm * 1024 + d;
        s += tbr[d] * (bf2f(Wath[o]) + bf2f(Watl[o]));
    }
    sb[t] = s; __syncthreads();
    for (int st = 128; st >= 1; st >>= 1) {
        if (t < st) sb[t] += sb[t + st];
        __syncthreads();
    }
    if (t == 0) bac2[pm] = bac[pm] + sb[0];
}

// t=0 stage A: hp = zxa * rw   (col_0 == 0)
__global__ void hp0_k(const u16* __restrict__ zxah, const u16* __restrict__ zxal,
                      const float* __restrict__ rw,
                      u16* __restrict__ hph, u16* __restrict__ hpl)
{
    int idx = blockIdx.x * 256 + threadIdx.x;   // ushort4 index over Nn*Kc/4
    if (idx >= Nn * Kc / 4) return;
    int c4 = idx % (Kc / 4);                    // 576
    int n  = idx / (Kc / 4);
    float w = rw[(long)n * Pp + (c4 >> 6)];     // p = (c4*4)>>8
    ushort4 zh = ((const ushort4*)zxah)[idx], zl = ((const ushort4*)zxal)[idx];
    ushort4 h4, l4;
    split2((bf2f(zh.x) + bf2f(zl.x)) * w, h4.x, l4.x);
    split2((bf2f(zh.y) + bf2f(zl.y)) * w, h4.y, l4.y);
    split2((bf2f(zh.z) + bf2f(zl.z)) * w, h4.z, l4.z);
    split2((bf2f(zh.w) + bf2f(zl.w)) * w, h4.w, l4.w);
    ((ushort4*)hph)[idx] = h4; ((ushort4*)hpl)[idx] = l4;
}

// ---------------- neighbor mixer -> split bf16 ----------------
__global__ void mixer_k(const float* __restrict__ x, const float* __restrict__ mw,
                        u16* __restrict__ xmh, u16* __restrict__ xml)
{
    int idx = blockIdx.x * 256 + threadIdx.x;       // float4 index, total N*D/4
    if (idx >= Nn * Dd / 4) return;
    int d4 = idx & (Dd / 4 - 1);
    int n = idx >> 8;
    int s = n & 2047;                               // S=2048
    const float4* x4 = (const float4*)x;
    const float4* w4 = (const float4*)mw;
    float4 xc = x4[idx];
    float4 w0 = w4[d4], w1 = w4[(Dd / 4) + d4], w2 = w4[2 * (Dd / 4) + d4];
    float o[4];
    o[0] = xc.x * w0.x; o[1] = xc.y * w0.y; o[2] = xc.z * w0.z; o[3] = xc.w * w0.w;
    if (s > 0) {
        float4 xl = x4[idx - Dd / 4];
        o[0] += xl.x * w1.x; o[1] += xl.y * w1.y; o[2] += xl.z * w1.z; o[3] += xl.w * w1.w;
    }
    if (s < 2047) {
        float4 xr = x4[idx + Dd / 4];
        o[0] += xr.x * w2.x; o[1] += xr.y * w2.y; o[2] += xr.z * w2.z; o[3] += xr.w * w2.w;
    }
    ushort4 h4, l4;
    split2(o[0], h4.x, l4.x); split2(o[1], h4.y, l4.y);
    split2(o[2], h4.z, l4.z); split2(o[3], h4.w, l4.w);
    ((ushort4*)xmh)[idx] = h4; ((ushort4*)xml)[idx] = l4;
}

__global__ void tanh_k(const float* __restrict__ a, float* __restrict__ o, int total)
{
    int idx = blockIdx.x * 256 + threadIdx.x;
    if (idx < total) o[idx] = tanhf(a[idx]);
}

// tin = recompose(xm) + tbr  -> split  (fallback path only)
__global__ void addb_split_k(const u16* __restrict__ xmh, const u16* __restrict__ xml,
                             const float* __restrict__ tbr,
                             u16* __restrict__ th_, u16* __restrict__ tl_)
{
    int idx = blockIdx.x * 256 + threadIdx.x;
    if (idx >= Nn * Dd / 4) return;
    int d4 = idx & (Dd / 4 - 1);
    ushort4 xh = ((const ushort4*)xmh)[idx], xl = ((const ushort4*)xml)[idx];
    float4 b = ((const float4*)tbr)[d4];
    ushort4 h4, l4;
    split2(bf2f(xh.x) + bf2f(xl.x) + b.x, h4.x, l4.x);
    split2(bf2f(xh.y) + bf2f(xl.y) + b.y, h4.y, l4.y);
    split2(bf2f(xh.z) + bf2f(xl.z) + b.z, h4.z, l4.z);
    split2(bf2f(xh.w) + bf2f(xl.w) + b.w, h4.w, l4.w);
    ((ushort4*)th_)[idx] = h4; ((ushort4*)tl_)[idx] = l4;
}

// ============ mgemm (r5 structure: 128x128, 4 waves, dbuf, vmcnt(8)) ============
// EPI 0: Cf = acc + bias                                   (zx)
// EPI 1: Cf = tanh(acc + Cinit)                            (obs)
// EPI 2: split: acc + CIsplit + bias                       (twist; fallback)
// EPI 3: split: (acc + bias) * rw[r][c>>8]                 (stage A; fallback)
// EPI 4: dual-acc per-p rescale rwv + sum_p rwv2*bbr -> Cf (final routing)
// EPI 5: Cf = acc + sum_p rwv*bbr                          (stage B)
// EPI 6: split: acc (+bias if non-null)                    (Wfat, zxa)
// EPI 7: split: (acc + CIsplit) * rw[r][c>>8]              (stage A', new)
template<int EPI>
__global__ __launch_bounds__(256, 2) void mgemm(
    const u16* __restrict__ Agh, const u16* __restrict__ Agl, int lda,
    const u16* __restrict__ Bgh, const u16* __restrict__ Bgl, int ldb,
    int K,
    float* __restrict__ Cf, u16* __restrict__ Coh, u16* __restrict__ Col, int ldc,
    const float* __restrict__ Cinit,
    const u16* __restrict__ CIh, const u16* __restrict__ CIl,
    const float* __restrict__ bias,
    const float* __restrict__ rwv,
    const float* __restrict__ rwv2,
    const float* __restrict__ bbrv)
{
    __shared__ u16 smem[2][16384];
    const int tid = threadIdx.x, wave = tid >> 6, lane = tid & 63;
    const int nwg = gridDim.x * gridDim.y;
    const int flat = blockIdx.y * gridDim.x + blockIdx.x;
    const int q = nwg >> 3;
    const int l_ = (flat & 7) * q + (flat >> 3);
    const int r0 = (l_ / gridDim.x) * 128, c0 = (l_ % gridDim.x) * 128;
    const int srl = lane >> 2;
    const int ssl = ((lane & 3) ^ ((lane >> 3) & 3)) * 8;
    const int frl = lane & 15, kh = lane >> 4;
    const int sw  = (kh ^ ((frl >> 1) & 3)) * 8;
    const int arow0 = (wave >> 1) * 64, bcol0 = (wave & 1) * 64;
    const int w32 = wave * 32;

    f32x4 acc[4][4] = {};
    f32x4 acc2[4][4];
    if constexpr (EPI == 4) {
#pragma unroll
        for (int i = 0; i < 4; ++i)
#pragma unroll
            for (int j = 0; j < 4; ++j) acc2[i][j] = f32x4{0.f, 0.f, 0.f, 0.f};
    }

    auto STAGE = [&](int buf, int k0) {
        u16* base = &smem[buf][0];
        u16* As_h = base;        u16* As_l = base + 4096;
        u16* Bs_h = base + 8192; u16* Bs_l = base + 12288;
        const long ga0 = (long)(r0 + w32 + srl) * lda + k0 + ssl;
        gld16(&As_h[w32 * 32],        Agh + ga0);
        gld16(&As_h[(w32 + 16) * 32], Agh + ga0 + 16L * lda);
        gld16(&As_l[w32 * 32],        Agl + ga0);
        gld16(&As_l[(w32 + 16) * 32], Agl + ga0 + 16L * lda);
        const long gb0 = (long)(c0 + w32 + srl) * ldb + k0 + ssl;
        gld16(&Bs_h[w32 * 32],        Bgh + gb0);
        gld16(&Bs_h[(w32 + 16) * 32], Bgh + gb0 + 16L * ldb);
        gld16(&Bs_l[w32 * 32],        Bgl + gb0);
        gld16(&Bs_l[(w32 + 16) * 32], Bgl + gb0 + 16L * ldb);
    };
    auto COMPUTE = [&](int buf, f32x4 (&ac)[4][4]) {
        u16* base = &smem[buf][0];
        u16* As_h = base;        u16* As_l = base + 4096;
        u16* Bs_h = base + 8192; u16* Bs_l = base + 12288;
        bf16x8 ah[4], al[4];
#pragma unroll
        for (int f = 0; f < 4; ++f) {
            int ao = (arow0 + f * 16 + frl) * 32 + sw;
            ah[f] = *(const bf16x8*)&As_h[ao];
            al[f] = *(const bf16x8*)&As_l[ao];
        }
#pragma unroll
        for (int j = 0; j < 4; ++j) {
            int bo = (bcol0 + j * 16 + frl) * 32 + sw;
            bf16x8 bh = *(const bf16x8*)&Bs_h[bo];
            bf16x8 bl = *(const bf16x8*)&Bs_l[bo];
#pragma unroll
            for (int i = 0; i < 4; ++i) {
                ac[i][j] = __builtin_amdgcn_mfma_f32_16x16x32_bf16(ah[i], bh, ac[i][j], 0, 0, 0);
                ac[i][j] = __builtin_amdgcn_mfma_f32_16x16x32_bf16(ah[i], bl, ac[i][j], 0, 0, 0);
                ac[i][j] = __builtin_amdgcn_mfma_f32_16x16x32_bf16(al[i], bh, ac[i][j], 0, 0, 0);
            }
        }
    };
    auto FLUSH = [&](int p) {
#pragma unroll
        for (int i = 0; i < 4; ++i)
#pragma unroll
            for (int reg = 0; reg < 4; ++reg) {
                float w = rwv[(long)(r0 + arow0 + i * 16 + kh * 4 + reg) * 9 + p];
#pragma unroll
                for (int j = 0; j < 4; ++j) {
                    acc[i][j][reg] += w * acc2[i][j][reg];
                    acc2[i][j][reg] = 0.f;
                }
            }
    };

    const int NT = K / 32;
    STAGE(0, 0);
#pragma unroll 1
    for (int t = 0; t < NT; t += 2) {
        STAGE(1, (t + 1) * 32);
        asm volatile("s_waitcnt vmcnt(8)" ::: "memory");
        __builtin_amdgcn_sched_barrier(0);
        __builtin_amdgcn_s_barrier();
        __builtin_amdgcn_sched_barrier(0);
        if constexpr (EPI == 4) COMPUTE(0, acc2); else COMPUTE(0, acc);
        __builtin_amdgcn_sched_barrier(0);
        __builtin_amdgcn_s_barrier();
        __builtin_amdgcn_sched_barrier(0);
        if (t + 2 < NT) {
            STAGE(0, (t + 2) * 32);
            asm volatile("s_waitcnt vmcnt(8)" ::: "memory");
        } else {
            asm volatile("s_waitcnt vmcnt(0)" ::: "memory");
        }
        __builtin_amdgcn_sched_barrier(0);
        __builtin_amdgcn_s_barrier();
        __builtin_amdgcn_sched_barrier(0);
        if constexpr (EPI == 4) COMPUTE(1, acc2); else COMPUTE(1, acc);
        __builtin_amdgcn_sched_barrier(0);
        __builtin_amdgcn_s_barrier();
        __builtin_amdgcn_sched_barrier(0);
        if constexpr (EPI == 4) {
            if (((t + 1) & 7) == 7) FLUSH((t + 1) >> 3);
        }
    }

#pragma unroll
    for (int i = 0; i < 4; ++i)
#pragma unroll
        for (int reg = 0; reg < 4; ++reg) {
            const int r = r0 + arow0 + i * 16 + kh * 4 + reg;
#pragma unroll
            for (int j = 0; j < 4; ++j) {
                const int c = c0 + bcol0 + j * 16 + frl;
                const long o = (long)r * ldc + c;
                float v = acc[i][j][reg];
                if constexpr (EPI == 0) {
                    Cf[o] = v + bias[c];
                } else if constexpr (EPI == 1) {
                    Cf[o] = tanhf(v + Cinit[o]);
                } else if constexpr (EPI == 2) {
                    v += bf2f(CIh[o]) + bf2f(CIl[o]) + bias[c];
                    u16 h, l; split2(v, h, l); Coh[o] = h; Col[o] = l;
                } else if constexpr (EPI == 3) {
                    v = (v + bias[c]) * rwv[(long)r * 9 + (c >> 8)];
                    u16 h, l; split2(v, h, l); Coh[o] = h; Col[o] = l;
                } else if constexpr (EPI == 4) {
#pragma unroll
                    for (int p = 0; p < 9; ++p) v += rwv2[(long)r * 9 + p] * bbrv[p * 1024 + c];
                    Cf[o] = v;
                } else if constexpr (EPI == 5) {
#pragma unroll
                    for (int p = 0; p < 9; ++p) v += rwv[(long)r * 9 + p] * bbrv[p * 1024 + c];
                    Cf[o] = v;
                } else if constexpr (EPI == 6) {
                    if (bias) v += bias[c];
                    u16 h, l; split2(v, h, l); Coh[o] = h; Col[o] = l;
                } else {            // EPI 7
                    v = (v + bf2f(CIh[o]) + bf2f(CIl[o])) * rwv[(long)r * 9 + (c >> 8)];
                    u16 h, l; split2(v, h, l); Coh[o] = h; Col[o] = l;
                }
            }
        }
}

// ---------------- logits + softmax / hard ----------------
__global__ void logits_k(const float* __restrict__ h, const float* __restrict__ W2r,
                         const float* __restrict__ b2r, const float* __restrict__ gum,
                         float* __restrict__ rwA, float* __restrict__ rwH,
                         const float* __restrict__ rwS, int hard)
{
    __shared__ float hs[Mm];
    __shared__ float lg[16];
    int n = blockIdx.x;
    for (int i = threadIdx.x; i < Mm; i += 64) hs[i] = h[(long)n * Mm + i];
    __syncthreads();
    if (threadIdx.x < Pp) {
        int p = threadIdx.x;
        float acc = b2r[p];
        for (int m = 0; m < Mm; ++m) acc += hs[m] * W2r[m * Pp + p];
        lg[p] = acc + gum[(long)n * Pp + p];
    }
    __syncthreads();
    if (threadIdx.x == 0) {
        float mx = lg[0]; int am = 0;
#pragma unroll
        for (int p = 1; p < Pp; ++p) if (lg[p] > mx) { mx = lg[p]; am = p; }
        if (hard) {
#pragma unroll
            for (int p = 0; p < Pp; ++p) {
                rwA[(long)n * Pp + p] = (p == am) ? 1.f / rwS[(long)n * Pp + p] : 0.f;
                rwH[(long)n * Pp + p] = (p == am) ? 1.f : 0.f;
            }
        } else {
            float e[Pp]; float ssum = 0.f;
#pragma unroll
            for (int p = 0; p < Pp; ++p) { e[p] = expf(lg[p] - mx); ssum += e[p]; }
#pragma unroll
            for (int p = 0; p < Pp; ++p) rwA[(long)n * Pp + p] = e[p] / ssum;
        }
    }
}

// ---------------- mod-phase RMS norm (group = d % 7) ----------------
template<int INSPLIT, int OUTSPLIT>
__global__ void norm_k(const float* __restrict__ in,
                       const u16* __restrict__ inh, const u16* __restrict__ inl,
                       const float* __restrict__ add, const float* __restrict__ g,
                       float* __restrict__ outf, u16* __restrict__ oh, u16* __restrict__ ol)
{
    __shared__ float sb[256][8];
    __shared__ float dn[8];
    int n = blockIdx.x;
    int t = threadIdx.x;
    float v[4];
#pragma unroll
    for (int j = 0; j < 7; ++j) sb[t][j] = 0.f;
#pragma unroll
    for (int i = 0; i < 4; ++i) {
        int d = t + i * 256;
        long o = (long)n * Dd + d;
        float xv = INSPLIT ? (bf2f(inh[o]) + bf2f(inl[o])) : in[o];
        if (add) xv += add[o];
        v[i] = xv;
        sb[t][d % 7] += xv * xv;
    }
    __syncthreads();
    for (int st = 128; st >= 1; st >>= 1) {
        if (t < st) {
#pragma unroll
            for (int j = 0; j < 7; ++j) sb[t][j] += sb[t + st][j];
        }
        __syncthreads();
    }
    if (t < 7) {
        const float cnt = (t < 2) ? 147.f : 146.f;
        dn[t] = 1.f / sqrtf(sb[0][t] / cnt + EPSf);
    }
    __syncthreads();
#pragma unroll
    for (int i = 0; i < 4; ++i) {
        int d = t + i * 256;
        long o = (long)n * Dd + d;
        float ov = v[i] * dn[d % 7] * g[d];
        if (OUTSPLIT) { u16 h, l; split2(ov, h, l); oh[o] = h; ol[o] = l; }
        else outf[o] = ov;
    }
}

static inline int cdiv(long a, long b) { return (int)((a + b - 1) / b); }
static inline size_t al256(size_t b) { return (b + 255) & ~(size_t)255; }

extern "C" void kernel_launch(void* const* d_in, const int* in_sizes, int n_in,
                              void* d_out, int out_size, void* d_ws, size_t ws_size,
                              hipStream_t stream)
{
    const float* x    = (const float*)d_in[0];
    const float* gum  = (const float*)d_in[1];
    const float* mw   = (const float*)d_in[2];
    const float* W1   = (const float*)d_in[3];
    const float* b1   = (const float*)d_in[4];
    const float* th1  = (const float*)d_in[5];
    const float* W2   = (const float*)d_in[6];
    const float* b2   = (const float*)d_in[7];
    const float* th2  = (const float*)d_in[8];
    const float* Wa   = (const float*)d_in[9];
    const float* ba   = (const float*)d_in[10];
    const float* tha  = (const float*)d_in[11];
    const float* Wb   = (const float*)d_in[12];
    const float* bbv  = (const float*)d_in[13];
    const float* thb  = (const float*)d_in[14];
    const float* tW   = (const float*)d_in[15];
    const float* tb   = (const float*)d_in[16];
    const float* tth  = (const float*)d_in[17];
    const float* gnorm = (const float*)d_in[18];

    // ---- workspace plan ----
    const size_t szRegion = al256((size_t)Nn * Dd * 4);
    const size_t szZx   = al256((size_t)Nn * Mm * 4);
    const size_t szRw   = al256((size_t)Nn * Pp * 4);
    const size_t szColH = al256((size_t)Nn * Dd * 2);
    const size_t szHpH  = al256((size_t)Nn * Kc * 2);
    const size_t szW1H  = al256((size_t)256 * 2048 * 2);
    const size_t szWatH = al256((size_t)Kc * 1024 * 2);
    const size_t szWbH  = al256((size_t)1024 * Kc * 2);
    const size_t szTWH  = al256((size_t)1024 * 1024 * 2);
    const size_t szMisc = al256(256 * 9 * 4) + al256(256 * 4) + al256(64)
                        + al256(Kc * 4) + al256(Kc * 4) + al256(Pp * 1024 * 4) + al256(1024 * 4);
    const size_t need_common = szRegion + szZx + 3 * szRw + 2 * szColH + 2 * szHpH
                             + 2 * szW1H + 2 * szWatH + 2 * szWbH + szMisc;
    const size_t need_new = 2 * szHpH /*zxa*/ + 2 * szTWH /*tWtT*/ + 2 * szWatH /*Wfat*/;
    const size_t need_old = 2 * szColH /*xm*/ + 2 * szTWH /*tWt*/;
    const bool NEWP = ws_size >= need_common + need_new;
    if (!NEWP && ws_size < need_common + need_old) return;

    char* cur = (char*)d_ws;
    auto alloc = [&](size_t bytes) -> void* { void* r = cur; cur += al256(bytes); return r; };

    void* region = alloc((size_t)Nn * Dd * 4);
    float* zx   = (float*)alloc((size_t)Nn * Mm * 4);
    float* rwS  = (float*)alloc((size_t)Nn * Pp * 4);
    float* rwD  = (float*)alloc((size_t)Nn * Pp * 4);
    float* rwH  = (float*)alloc((size_t)Nn * Pp * 4);
    u16* colh = (u16*)alloc((size_t)Nn * Dd * 2);
    u16* coll = (u16*)alloc((size_t)Nn * Dd * 2);
    u16* hph  = (u16*)alloc((size_t)Nn * Kc * 2);
    u16* hpl  = (u16*)alloc((size_t)Nn * Kc * 2);
    u16* W1th = (u16*)alloc(256 * 2048 * 2);
    u16* W1tl = (u16*)alloc(256 * 2048 * 2);
    u16* Wath = (u16*)alloc((size_t)Kc * 1024 * 2);
    u16* Watl = (u16*)alloc((size_t)Kc * 1024 * 2);
    u16* Wbth = (u16*)alloc((size_t)1024 * Kc * 2);
    u16* Wbtl = (u16*)alloc((size_t)1024 * Kc * 2);
    float* W2r  = (float*)alloc(256 * 9 * 4);
    float* b1r  = (float*)alloc(256 * 4);
    float* b2r  = (float*)alloc(64);
    float* bac  = (float*)alloc(Kc * 4);
    float* bac2 = (float*)alloc(Kc * 4);
    float* bbr  = (float*)alloc(Pp * 1024 * 4);
    float* tbr  = (float*)alloc(1024 * 4);

    float* hbuf = (float*)region;
    float* craw = (float*)region;
    float* out0 = (float*)d_out;
    float* out1 = out0 + (long)Nn * Dd;

    // ---- shared prep ----
    splitW1_k<<<2048, 256, 0, stream>>>(W1, th1, W1th, W1tl);
    splitWa_k<<<cdiv((long)Kc * 1024, 256), 256, 0, stream>>>(Wa, tha, Wath, Watl);
    splitWb_k<<<cdiv((long)1024 * Kc, 256), 256, 0, stream>>>(Wb, thb, Wbth, Wbtl);
    rotcopy_k<<<cdiv(256L * 9, 256), 256, 0, stream>>>(W2, W2r, 256, 9, th2, 1);
    rotcopy_k<<<1, 256, 0, stream>>>(b1, b1r, 1, 256, th1, 1);
    rotcopy_k<<<1, 256, 0, stream>>>(b2, b2r, 1, 9, th2, 1);
    rotcopy_k<<<cdiv((long)Pp * Mm, 256), 256, 0, stream>>>(ba, bac, 1, 256, tha, 9);
    rotcopy_k<<<cdiv((long)Pp * 1024, 256), 256, 0, stream>>>(bbv, bbr, 1, 1024, thb, 9);
    rotcopy_k<<<cdiv(1024L, 256), 256, 0, stream>>>(tb, tbr, 1, 1024, tth, 1);

    if (NEWP) {
        // ======== new plan: twist folded into stage A via Wfat/zxa ========
        u16* zxah  = (u16*)alloc((size_t)Nn * Kc * 2);
        u16* zxal  = (u16*)alloc((size_t)Nn * Kc * 2);
        u16* tWtTh = (u16*)alloc((size_t)1024 * 1024 * 2);
        u16* tWtTl = (u16*)alloc((size_t)1024 * 1024 * 2);
        u16* Wfath = (u16*)alloc((size_t)Kc * 1024 * 2);
        u16* Wfatl = (u16*)alloc((size_t)Kc * 1024 * 2);
        u16* xmh = (u16*)region;                    // xm lives in region, dead
        u16* xml = xmh + (size_t)Nn * Dd;           // before hbuf/craw first write

        splitTWT_k<<<4096, 256, 0, stream>>>(tW, tth, tWtTh, tWtTl);
        // Wfat[pm,e] = sum_d Wat[pm,d] * tWtT[e,d]
        mgemm<6><<<dim3(8, 18), 256, 0, stream>>>(
            Wath, Watl, 1024, tWtTh, tWtTl, 1024, 1024,
            nullptr, Wfath, Wfatl, 1024, nullptr, nullptr, nullptr,
            nullptr, nullptr, nullptr, nullptr);
        bac2_k<<<Kc, 256, 0, stream>>>(bac, tbr, Wath, Watl, bac2);

        mixer_k<<<Nn * Dd / 4 / 256, 256, 0, stream>>>(x, mw, xmh, xml);
        // zx = xm @ W1_top + b1r
        mgemm<0><<<dim3(2, 64), 256, 0, stream>>>(
            xmh, xml, 1024, W1th, W1tl, 2048, 1024,
            zx, nullptr, nullptr, 256, nullptr, nullptr, nullptr,
            b1r, nullptr, nullptr, nullptr);
        // zxa = xm @ Wat + bac2   (split out)  — must finish before tanh clobbers xm
        mgemm<6><<<dim3(18, 64), 256, 0, stream>>>(
            xmh, xml, 1024, Wath, Watl, 1024, 1024,
            nullptr, zxah, zxal, Kc, nullptr, nullptr, nullptr,
            bac2, nullptr, nullptr, nullptr);

        for (int t = 0; t < 3; ++t) {
            if (t == 0) {
                tanh_k<<<cdiv((long)Nn * Mm, 256), 256, 0, stream>>>(zx, hbuf, Nn * Mm);
            } else {
                mgemm<1><<<dim3(2, 64), 256, 0, stream>>>(
                    colh, coll, 1024, W1th + 1024, W1tl + 1024, 2048, 1024,
                    hbuf, nullptr, nullptr, 256, zx, nullptr, nullptr,
                    nullptr, nullptr, nullptr, nullptr);
            }
            logits_k<<<Nn, 64, 0, stream>>>(hbuf, W2r, b2r, gum + (long)t * Nn * Pp,
                                            rwS, nullptr, nullptr, 0);
            if (t == 0) {
                hp0_k<<<cdiv((long)Nn * Kc / 4, 256), 256, 0, stream>>>(zxah, zxal, rwS, hph, hpl);
            } else {
                // hp = (zxa + col @ Wfat) * rw
                mgemm<7><<<dim3(18, 64), 256, 0, stream>>>(
                    colh, coll, 1024, Wfath, Wfatl, 1024, 1024,
                    nullptr, hph, hpl, Kc, nullptr, zxah, zxal,
                    nullptr, rwS, nullptr, nullptr);
            }
            // craw = hp @ Wbt + sum_p rw_p bbr_p
            mgemm<5><<<dim3(8, 64), 256, 0, stream>>>(
                hph, hpl, Kc, Wbth, Wbtl, Kc, Kc,
                craw, nullptr, nullptr, 1024, nullptr, nullptr, nullptr,
                nullptr, rwS, nullptr, bbr);
            norm_k<0, 1><<<Nn, 256, 0, stream>>>(craw, nullptr, nullptr, nullptr, gnorm,
                                                 nullptr, colh, coll);
        }
        // final hard routing
        mgemm<1><<<dim3(2, 64), 256, 0, stream>>>(
            colh, coll, 1024, W1th + 1024, W1tl + 1024, 2048, 1024,
            hbuf, nullptr, nullptr, 256, zx, nullptr, nullptr,
            nullptr, nullptr, nullptr, nullptr);
        logits_k<<<Nn, 64, 0, stream>>>(hbuf, W2r, b2r, gum + 3L * Nn * Pp, rwD, rwH, rwS, 1);
        mgemm<4><<<dim3(8, 64), 256, 0, stream>>>(
            hph, hpl, Kc, Wbth, Wbtl, Kc, Kc,
            craw, nullptr, nullptr, 1024, nullptr, nullptr, nullptr,
            nullptr, rwD, rwH, bbr);
        norm_k<0, 0><<<Nn, 256, 0, stream>>>(craw, nullptr, nullptr, x, gnorm, out0, nullptr, nullptr);
        norm_k<1, 0><<<Nn, 256, 0, stream>>>(nullptr, colh, coll, nullptr, gnorm, out1, nullptr, nullptr);
    } else {
        // ======== fallback: proven r5 flow ========
        u16* xmh  = (u16*)alloc((size_t)Nn * Dd * 2);
        u16* xml  = (u16*)alloc((size_t)Nn * Dd * 2);
        u16* tWth = (u16*)alloc((size_t)1024 * 1024 * 2);
        u16* tWtl = (u16*)alloc((size_t)1024 * 1024 * 2);
        u16* tinh = (u16*)region;
        u16* tinl = tinh + (size_t)Nn * Dd;

        splitTW_k<<<4096, 256, 0, stream>>>(tW, tth, tWth, tWtl);
        mixer_k<<<Nn * Dd / 4 / 256, 256, 0, stream>>>(x, mw, xmh, xml);
        mgemm<0><<<dim3(2, 64), 256, 0, stream>>>(
            xmh, xml, 1024, W1th, W1tl, 2048, 1024,
            zx, nullptr, nullptr, 256, nullptr, nullptr, nullptr,
            b1r, nullptr, nullptr, nullptr);

        for (int t = 0; t < 3; ++t) {
            if (t == 0) {
                tanh_k<<<cdiv((long)Nn * Mm, 256), 256, 0, stream>>>(zx, hbuf, Nn * Mm);
            } else {
                mgemm<1><<<dim3(2, 64), 256, 0, stream>>>(
                    colh, coll, 1024, W1th + 1024, W1tl + 1024, 2048, 1024,
                    hbuf, nullptr, nullptr, 256, zx, nullptr, nullptr,
                    nullptr, nullptr, nullptr, nullptr);
            }
            logits_k<<<Nn, 64, 0, stream>>>(hbuf, W2r, b2r, gum + (long)t * Nn * Pp,
                                            rwS, nullptr, nullptr, 0);
            if (t == 0) {
                addb_split_k<<<Nn * Dd / 4 / 256, 256, 0, stream>>>(xmh, xml, tbr, tinh, tinl);
            } else {
                mgemm<2><<<dim3(8, 64), 256, 0, stream>>>(
                    colh, coll, 1024, tWth, tWtl, 1024, 1024,
                    nullptr, tinh, tinl, 1024, nullptr, xmh, xml,
                    tbr, nullptr, nullptr, nullptr);
            }
            mgemm<3><<<dim3(18, 64), 256, 0, stream>>>(
                tinh, tinl, 1024, Wath, Watl, 1024, 1024,
                nullptr, hph, hpl, Kc, nullptr, nullptr, nullptr,
                bac, rwS, nullptr, nullptr);
            mgemm<5><<<dim3(8, 64), 256, 0, stream>>>(
                hph, hpl, Kc, Wbth, Wbtl, Kc, Kc,
                craw, nullptr, nullptr, 1024, nullptr, nullptr, nullptr,
                nullptr, rwS, nullptr, bbr);
            norm_k<0, 1><<<Nn, 256, 0, stream>>>(craw, nullptr, nullptr, nullptr, gnorm,
                                                 nullptr, colh, coll);
        }
        mgemm<1><<<dim3(2, 64), 256, 0, stream>>>(
            colh, coll, 1024, W1th + 1024, W1tl + 1024, 2048, 1024,
            hbuf, nullptr, nullptr, 256, zx, nullptr, nullptr,
            nullptr, nullptr, nullptr, nullptr);
        logits_k<<<Nn, 64, 0, stream>>>(hbuf, W2r, b2r, gum + 3L * Nn * Pp, rwD, rwH, rwS, 1);
        mgemm<4><<<dim3(8, 64), 256, 0, stream>>>(
            hph, hpl, Kc, Wbth, Wbtl, Kc, Kc,
            craw, nullptr, nullptr, 1024, nullptr, nullptr, nullptr,
            nullptr, rwD, rwH, bbr);
        norm_k<0, 0><<<Nn, 256, 0, stream>>>(craw, nullptr, nullptr, x, gnorm, out0, nullptr, nullptr);
        norm_k<1, 0><<<Nn, 256, 0, stream>>>(nullptr, colh, coll, nullptr, gnorm, out1, nullptr, nullptr);
    }
}

// Round 12
// 1332.555 us; speedup vs baseline: 1.0986x; 1.0580x over previous
//
#include <hip/hip_runtime.h>
#include <hip/hip_bf16.h>

// MobiusCollapseLayer: B=4,S=2048,D=1024,P=9,M=256, 3 twists. N=8192 tokens.
// Round 12: (1) bucketed final routing (one-hot => K=256 GEMM via argmax
// compaction, indirect rows, masked scatter writes); (2) skinny 64x128 GEMM
// for obs/zx (full-GPU grids). Heavy GEMMs unchanged (r5 structure).
typedef unsigned short u16;
typedef short bf16x8 __attribute__((ext_vector_type(8)));
typedef float f32x4 __attribute__((ext_vector_type(4)));

constexpr int Dd = 1024, Pp = 9, Mm = 256, Nn = 8192, Kc = 2304;
constexpr int CAP = 4096;                  // bucket capacity (binomial 4-sigma ~1024)
constexpr float EPSf = 1e-6f;

__device__ __forceinline__ float bf2f(u16 u) {
    union { unsigned int u; float f; } v; v.u = ((unsigned int)u) << 16; return v.f;
}
__device__ __forceinline__ u16 f2bf(float f) {
    union { float f; unsigned int u; } v; v.f = f;
    unsigned int r = (v.u + 0x7FFFu + ((v.u >> 16) & 1u)) >> 16; return (u16)r;
}
__device__ __forceinline__ void split2(float v, u16& h, u16& l) {
    h = f2bf(v); l = f2bf(v - bf2f(h));
}
__device__ __forceinline__ void gld16(u16* lds, const u16* g) {
    __builtin_amdgcn_global_load_lds(
        (const __attribute__((address_space(1))) unsigned int*)g,
        (__attribute__((address_space(3))) unsigned int*)lds, 16, 0, 0);
}

// ---------------- weight prep ----------------
__global__ void rotcopy_k(const float* __restrict__ src, float* __restrict__ dst,
                          int R, int C, const float* __restrict__ theta, int Pb)
{
    long total = (long)Pb * R * C;
    long idx = (long)blockIdx.x * 256 + threadIdx.x;
    if (idx >= total) return;
    int c = (int)(idx % C);
    long rp = idx / C;
    int r = (int)(rp % R);
    int pb = (int)(rp / R);
    float th = theta[pb];
    const float* s = src + ((long)pb * R + r) * C;
    float v;
    if (c == 0)      v = s[0] * cosf(th) - s[1] * sinf(th);
    else if (c == 1) v = s[0] * sinf(th) + s[1] * cosf(th);
    else             v = s[c];
    dst[idx] = v;
}

__global__ void splitW1_k(const float* __restrict__ W1, const float* __restrict__ th,
                          u16* __restrict__ h, u16* __restrict__ l)
{
    int idx = blockIdx.x * 256 + threadIdx.x;
    if (idx >= 256 * 2048) return;
    int k = idx & 2047, n = idx >> 11;
    float v;
    if (n == 0)      v = W1[(long)k * 256 + 0] * cosf(th[0]) - W1[(long)k * 256 + 1] * sinf(th[0]);
    else if (n == 1) v = W1[(long)k * 256 + 0] * sinf(th[0]) + W1[(long)k * 256 + 1] * cosf(th[0]);
    else             v = W1[(long)k * 256 + n];
    u16 hh, ll; split2(v, hh, ll); h[idx] = hh; l[idx] = ll;
}

// tWtT [e][d] = rot_d(tW[e][d])  (B operand for Wfat compute)
__global__ void splitTWT_k(const float* __restrict__ tW, const float* __restrict__ th,
                           u16* __restrict__ h, u16* __restrict__ l)
{
    int idx = blockIdx.x * 256 + threadIdx.x;
    if (idx >= 1024 * 1024) return;
    int d = idx & 1023, e = idx >> 10;
    const float* s = tW + (long)e * 1024;
    float v;
    if (d == 0)      v = s[0] * cosf(th[0]) - s[1] * sinf(th[0]);
    else if (d == 1) v = s[0] * sinf(th[0]) + s[1] * cosf(th[0]);
    else             v = s[d];
    u16 hh, ll; split2(v, hh, ll); h[idx] = hh; l[idx] = ll;
}

__global__ void splitWa_k(const float* __restrict__ Wa, const float* __restrict__ tha,
                          u16* __restrict__ h, u16* __restrict__ l)
{
    int idx = blockIdx.x * 256 + threadIdx.x;
    if (idx >= Kc * 1024) return;
    int k = idx & 1023, n = idx >> 10;
    int p = n >> 8, m = n & 255;
    const float* s = Wa + ((long)p * 1024 + k) * 256;
    float v;
    if (m == 0)      v = s[0] * cosf(tha[p]) - s[1] * sinf(tha[p]);
    else if (m == 1) v = s[0] * sinf(tha[p]) + s[1] * cosf(tha[p]);
    else             v = s[m];
    u16 hh, ll; split2(v, hh, ll); h[idx] = hh; l[idx] = ll;
}

__global__ void splitWb_k(const float* __restrict__ Wb, const float* __restrict__ thb,
                          u16* __restrict__ h, u16* __restrict__ l)
{
    int idx = blockIdx.x * 256 + threadIdx.x;
    if (idx >= 1024 * Kc) return;
    int n = idx / Kc;              // d
    int k = idx - n * Kc;          // p*256+m
    int p = k >> 8, m = k & 255;
    const float* s = Wb + ((long)p * 256 + m) * 1024;
    float v;
    if (n == 0)      v = s[0] * cosf(thb[p]) - s[1] * sinf(thb[p]);
    else if (n == 1) v = s[0] * sinf(thb[p]) + s[1] * cosf(thb[p]);
    else             v = s[n];
    u16 hh, ll; split2(v, hh, ll); h[idx] = hh; l[idx] = ll;
}

// bac2[pm] = bac[pm] + sum_d tbr[d] * Wat[pm,d]
__global__ void bac2_k(const float* __restrict__ bac, const float* __restrict__ tbr,
                       const u16* __restrict__ Wath, const u16* __restrict__ Watl,
                       float* __restrict__ bac2)
{
    __shared__ float sb[256];
    int pm = blockIdx.x;
    int t = threadIdx.x;
    float s = 0.f;
    for (int d = t; d < 1024; d += 256) {
        long o = (long)pm * 1024 + d;
        s += tbr[d] * (bf2f(Wath[o]) + bf2f(Watl[o]));
    }
    sb[t] = s; __syncthreads();
    for (int st = 128; st >= 1; st >>= 1) {
        if (t < st) sb[t] += sb[t + st];
        __syncthreads();
    }
    if (t == 0) bac2[pm] = bac[pm] + sb[0];
}

// t=0 stage A: hp = zxa * rw   (col_0 == 0)
__global__ void hp0_k(const u16* __restrict__ zxah, const u16* __restrict__ zxal,
                      const float* __restrict__ rw,
                      u16* __restrict__ hph, u16* __restrict__ hpl)
{
    int idx = blockIdx.x * 256 + threadIdx.x;   // ushort4 index over Nn*Kc/4
    if (idx >= Nn * Kc / 4) return;
    int c4 = idx % (Kc / 4);
    int n  = idx / (Kc / 4);
    float w = rw[(long)n * Pp + (c4 >> 6)];
    ushort4 zh = ((const ushort4*)zxah)[idx], zl = ((const ushort4*)zxal)[idx];
    ushort4 h4, l4;
    split2((bf2f(zh.x) + bf2f(zl.x)) * w, h4.x, l4.x);
    split2((bf2f(zh.y) + bf2f(zl.y)) * w, h4.y, l4.y);
    split2((bf2f(zh.z) + bf2f(zl.z)) * w, h4.z, l4.z);
    split2((bf2f(zh.w) + bf2f(zl.w)) * w, h4.w, l4.w);
    ((ushort4*)hph)[idx] = h4; ((ushort4*)hpl)[idx] = l4;
}

// ---------------- neighbor mixer -> split bf16 ----------------
__global__ void mixer_k(const float* __restrict__ x, const float* __restrict__ mw,
                        u16* __restrict__ xmh, u16* __restrict__ xml)
{
    int idx = blockIdx.x * 256 + threadIdx.x;
    if (idx >= Nn * Dd / 4) return;
    int d4 = idx & (Dd / 4 - 1);
    int n = idx >> 8;
    int s = n & 2047;
    const float4* x4 = (const float4*)x;
    const float4* w4 = (const float4*)mw;
    float4 xc = x4[idx];
    float4 w0 = w4[d4], w1 = w4[(Dd / 4) + d4], w2 = w4[2 * (Dd / 4) + d4];
    float o[4];
    o[0] = xc.x * w0.x; o[1] = xc.y * w0.y; o[2] = xc.z * w0.z; o[3] = xc.w * w0.w;
    if (s > 0) {
        float4 xl = x4[idx - Dd / 4];
        o[0] += xl.x * w1.x; o[1] += xl.y * w1.y; o[2] += xl.z * w1.z; o[3] += xl.w * w1.w;
    }
    if (s < 2047) {
        float4 xr = x4[idx + Dd / 4];
        o[0] += xr.x * w2.x; o[1] += xr.y * w2.y; o[2] += xr.z * w2.z; o[3] += xr.w * w2.w;
    }
    ushort4 h4, l4;
    split2(o[0], h4.x, l4.x); split2(o[1], h4.y, l4.y);
    split2(o[2], h4.z, l4.z); split2(o[3], h4.w, l4.w);
    ((ushort4*)xmh)[idx] = h4; ((ushort4*)xml)[idx] = l4;
}

__global__ void tanh_k(const float* __restrict__ a, float* __restrict__ o, int total)
{
    int idx = blockIdx.x * 256 + threadIdx.x;
    if (idx < total) o[idx] = tanhf(a[idx]);
}

// ============ mgemm (r5 structure: 128x128, 4 waves, dbuf, vmcnt(8)) ============
// EPI 5: Cf = acc + sum_p rwv*bbr            (stage B)
// EPI 6: split: acc (+bias if non-null)      (Wfat, zxa)
// EPI 7: split: (acc + CIsplit) * rw[r][c>>8]  (stage A')
template<int EPI>
__global__ __launch_bounds__(256, 2) void mgemm(
    const u16* __restrict__ Agh, const u16* __restrict__ Agl, int lda,
    const u16* __restrict__ Bgh, const u16* __restrict__ Bgl, int ldb,
    int K,
    float* __restrict__ Cf, u16* __restrict__ Coh, u16* __restrict__ Col, int ldc,
    const u16* __restrict__ CIh, const u16* __restrict__ CIl,
    const float* __restrict__ bias,
    const float* __restrict__ rwv,
    const float* __restrict__ bbrv)
{
    __shared__ u16 smem[2][16384];
    const int tid = threadIdx.x, wave = tid >> 6, lane = tid & 63;
    const int nwg = gridDim.x * gridDim.y;
    const int flat = blockIdx.y * gridDim.x + blockIdx.x;
    const int q = nwg >> 3;
    const int l_ = (flat & 7) * q + (flat >> 3);
    const int r0 = (l_ / gridDim.x) * 128, c0 = (l_ % gridDim.x) * 128;
    const int srl = lane >> 2;
    const int ssl = ((lane & 3) ^ ((lane >> 3) & 3)) * 8;
    const int frl = lane & 15, kh = lane >> 4;
    const int sw  = (kh ^ ((frl >> 1) & 3)) * 8;
    const int arow0 = (wave >> 1) * 64, bcol0 = (wave & 1) * 64;
    const int w32 = wave * 32;

    f32x4 acc[4][4] = {};

    auto STAGE = [&](int buf, int k0) {
        u16* base = &smem[buf][0];
        u16* As_h = base;        u16* As_l = base + 4096;
        u16* Bs_h = base + 8192; u16* Bs_l = base + 12288;
        const long ga0 = (long)(r0 + w32 + srl) * lda + k0 + ssl;
        gld16(&As_h[w32 * 32],        Agh + ga0);
        gld16(&As_h[(w32 + 16) * 32], Agh + ga0 + 16L * lda);
        gld16(&As_l[w32 * 32],        Agl + ga0);
        gld16(&As_l[(w32 + 16) * 32], Agl + ga0 + 16L * lda);
        const long gb0 = (long)(c0 + w32 + srl) * ldb + k0 + ssl;
        gld16(&Bs_h[w32 * 32],        Bgh + gb0);
        gld16(&Bs_h[(w32 + 16) * 32], Bgh + gb0 + 16L * ldb);
        gld16(&Bs_l[w32 * 32],        Bgl + gb0);
        gld16(&Bs_l[(w32 + 16) * 32], Bgl + gb0 + 16L * ldb);
    };
    auto COMPUTE = [&](int buf) {
        u16* base = &smem[buf][0];
        u16* As_h = base;        u16* As_l = base + 4096;
        u16* Bs_h = base + 8192; u16* Bs_l = base + 12288;
        bf16x8 ah[4], al[4];
#pragma unroll
        for (int f = 0; f < 4; ++f) {
            int ao = (arow0 + f * 16 + frl) * 32 + sw;
            ah[f] = *(const bf16x8*)&As_h[ao];
            al[f] = *(const bf16x8*)&As_l[ao];
        }
#pragma unroll
        for (int j = 0; j < 4; ++j) {
            int bo = (bcol0 + j * 16 + frl) * 32 + sw;
            bf16x8 bh = *(const bf16x8*)&Bs_h[bo];
            bf16x8 bl = *(const bf16x8*)&Bs_l[bo];
#pragma unroll
            for (int i = 0; i < 4; ++i) {
                acc[i][j] = __builtin_amdgcn_mfma_f32_16x16x32_bf16(ah[i], bh, acc[i][j], 0, 0, 0);
                acc[i][j] = __builtin_amdgcn_mfma_f32_16x16x32_bf16(ah[i], bl, acc[i][j], 0, 0, 0);
                acc[i][j] = __builtin_amdgcn_mfma_f32_16x16x32_bf16(al[i], bh, acc[i][j], 0, 0, 0);
            }
        }
    };

    const int NT = K / 32;
    STAGE(0, 0);
#pragma unroll 1
    for (int t = 0; t < NT; t += 2) {
        STAGE(1, (t + 1) * 32);
        asm volatile("s_waitcnt vmcnt(8)" ::: "memory");
        __builtin_amdgcn_sched_barrier(0);
        __builtin_amdgcn_s_barrier();
        __builtin_amdgcn_sched_barrier(0);
        COMPUTE(0);
        __builtin_amdgcn_sched_barrier(0);
        __builtin_amdgcn_s_barrier();
        __builtin_amdgcn_sched_barrier(0);
        if (t + 2 < NT) {
            STAGE(0, (t + 2) * 32);
            asm volatile("s_waitcnt vmcnt(8)" ::: "memory");
        } else {
            asm volatile("s_waitcnt vmcnt(0)" ::: "memory");
        }
        __builtin_amdgcn_sched_barrier(0);
        __builtin_amdgcn_s_barrier();
        __builtin_amdgcn_sched_barrier(0);
        COMPUTE(1);
        __builtin_amdgcn_sched_barrier(0);
        __builtin_amdgcn_s_barrier();
        __builtin_amdgcn_sched_barrier(0);
    }

#pragma unroll
    for (int i = 0; i < 4; ++i)
#pragma unroll
        for (int reg = 0; reg < 4; ++reg) {
            const int r = r0 + arow0 + i * 16 + kh * 4 + reg;
#pragma unroll
            for (int j = 0; j < 4; ++j) {
                const int c = c0 + bcol0 + j * 16 + frl;
                const long o = (long)r * ldc + c;
                float v = acc[i][j][reg];
                if constexpr (EPI == 5) {
#pragma unroll
                    for (int p = 0; p < 9; ++p) v += rwv[(long)r * 9 + p] * bbrv[p * 1024 + c];
                    Cf[o] = v;
                } else if constexpr (EPI == 6) {
                    if (bias) v += bias[c];
                    u16 h, l; split2(v, h, l); Coh[o] = h; Col[o] = l;
                } else {            // EPI 7
                    v = (v + bf2f(CIh[o]) + bf2f(CIl[o])) * rwv[(long)r * 9 + (c >> 8)];
                    u16 h, l; split2(v, h, l); Coh[o] = h; Col[o] = l;
                }
            }
        }
}

// ====== mgemmS: skinny 64x128 tile, 2 waves, for obs/zx (full-GPU grids) ======
// EPI 0: Cf = acc + bias     EPI 1: Cf = tanh(acc + Cinit)
template<int EPI>
__global__ __launch_bounds__(128, 2) void mgemmS(
    const u16* __restrict__ Agh, const u16* __restrict__ Agl, int lda,
    const u16* __restrict__ Bgh, const u16* __restrict__ Bgl, int ldb,
    int K,
    float* __restrict__ Cf, int ldc,
    const float* __restrict__ Cinit,
    const float* __restrict__ bias)
{
    __shared__ u16 smem[2][12288];   // Ah[64x32] Al Bh[128x32] Bl = 24KB/buf
    const int tid = threadIdx.x, wave = tid >> 6, lane = tid & 63;
    const int nwg = gridDim.x * gridDim.y;
    const int flat = blockIdx.y * gridDim.x + blockIdx.x;
    const int q = nwg >> 3;
    const int l_ = (flat & 7) * q + (flat >> 3);
    const int r0 = (l_ / gridDim.x) * 64, c0 = (l_ % gridDim.x) * 128;
    const int srl = lane >> 2;
    const int ssl = ((lane & 3) ^ ((lane >> 3) & 3)) * 8;
    const int frl = lane & 15, kh = lane >> 4;
    const int sw  = (kh ^ ((frl >> 1) & 3)) * 8;
    const int w32 = wave * 32, w64 = wave * 64;

    f32x4 acc[4][4] = {};

    auto STAGE = [&](int buf, int k0) {     // 12 gld16 per thread
        u16* Ash = &smem[buf][0];
        u16* Asl = &smem[buf][2048];
        u16* Bsh = &smem[buf][4096];
        u16* Bsl = &smem[buf][8192];
        const long ga = (long)(r0 + w32 + srl) * lda + k0 + ssl;
        gld16(&Ash[w32 * 32],        Agh + ga);
        gld16(&Ash[(w32 + 16) * 32], Agh + ga + 16L * lda);
        gld16(&Asl[w32 * 32],        Agl + ga);
        gld16(&Asl[(w32 + 16) * 32], Agl + ga + 16L * lda);
        const long gb = (long)(c0 + w64 + srl) * ldb + k0 + ssl;
        gld16(&Bsh[w64 * 32],        Bgh + gb);
        gld16(&Bsh[(w64 + 16) * 32], Bgh + gb + 16L * ldb);
        gld16(&Bsh[(w64 + 32) * 32], Bgh + gb + 32L * ldb);
        gld16(&Bsh[(w64 + 48) * 32], Bgh + gb + 48L * ldb);
        gld16(&Bsl[w64 * 32],        Bgl + gb);
        gld16(&Bsl[(w64 + 16) * 32], Bgl + gb + 16L * ldb);
        gld16(&Bsl[(w64 + 32) * 32], Bgl + gb + 32L * ldb);
        gld16(&Bsl[(w64 + 48) * 32], Bgl + gb + 48L * ldb);
    };
    auto COMPUTE = [&](int buf) {
        u16* Ash = &smem[buf][0];
        u16* Asl = &smem[buf][2048];
        u16* Bsh = &smem[buf][4096];
        u16* Bsl = &smem[buf][8192];
        bf16x8 ah[4], al[4];
#pragma unroll
        for (int f = 0; f < 4; ++f) {
            int ao = (f * 16 + frl) * 32 + sw;
            ah[f] = *(const bf16x8*)&Ash[ao];
            al[f] = *(const bf16x8*)&Asl[ao];
        }
#pragma unroll
        for (int j = 0; j < 4; ++j) {
            int bo = (w64 + j * 16 + frl) * 32 + sw;
            bf16x8 bh = *(const bf16x8*)&Bsh[bo];
            bf16x8 bl = *(const bf16x8*)&Bsl[bo];
#pragma unroll
            for (int i = 0; i < 4; ++i) {
                acc[i][j] = __builtin_amdgcn_mfma_f32_16x16x32_bf16(ah[i], bh, acc[i][j], 0, 0, 0);
                acc[i][j] = __builtin_amdgcn_mfma_f32_16x16x32_bf16(ah[i], bl, acc[i][j], 0, 0, 0);
                acc[i][j] = __builtin_amdgcn_mfma_f32_16x16x32_bf16(al[i], bh, acc[i][j], 0, 0, 0);
            }
        }
    };

    const int NT = K / 32;      // 32
    STAGE(0, 0);
#pragma unroll 1
    for (int t = 0; t < NT; t += 2) {
        STAGE(1, (t + 1) * 32);
        asm volatile("s_waitcnt vmcnt(12)" ::: "memory");
        __builtin_amdgcn_sched_barrier(0);
        __builtin_amdgcn_s_barrier();
        __builtin_amdgcn_sched_barrier(0);
        COMPUTE(0);
        __builtin_amdgcn_sched_barrier(0);
        __builtin_amdgcn_s_barrier();
        __builtin_amdgcn_sched_barrier(0);
        if (t + 2 < NT) {
            STAGE(0, (t + 2) * 32);
            asm volatile("s_waitcnt vmcnt(12)" ::: "memory");
        } else {
            asm volatile("s_waitcnt vmcnt(0)" ::: "memory");
        }
        __builtin_amdgcn_sched_barrier(0);
        __builtin_amdgcn_s_barrier();
        __builtin_amdgcn_sched_barrier(0);
        COMPUTE(1);
        __builtin_amdgcn_sched_barrier(0);
        __builtin_amdgcn_s_barrier();
        __builtin_amdgcn_sched_barrier(0);
    }

#pragma unroll
    for (int i = 0; i < 4; ++i)
#pragma unroll
        for (int reg = 0; reg < 4; ++reg) {
            const int r = r0 + i * 16 + kh * 4 + reg;
#pragma unroll
            for (int j = 0; j < 4; ++j) {
                const int c = c0 + w64 + j * 16 + frl;
                const long o = (long)r * ldc + c;
                float v = acc[i][j][reg];
                if constexpr (EPI == 0) Cf[o] = v + bias[c];
                else                    Cf[o] = tanhf(v + Cinit[o]);
            }
        }
}

// ====== final routing: bucketed K=256 GEMM with indirect rows ======
__global__ void bucket_k(const int* __restrict__ pstar, int* __restrict__ cnt,
                         int* __restrict__ perm)
{
    int n = blockIdx.x * 256 + threadIdx.x;
    if (n >= Nn) return;
    int p = pstar[n];
    int slot = atomicAdd(&cnt[p], 1);
    if (slot < CAP) perm[p * CAP + slot] = n;
}

__global__ __launch_bounds__(256, 2) void mgemm_fin(
    const u16* __restrict__ hph, const u16* __restrict__ hpl,     // [N][2304]
    const u16* __restrict__ Wbth, const u16* __restrict__ Wbtl,   // [1024][2304]
    const int* __restrict__ perm, const int* __restrict__ cnt,
    const float* __restrict__ rwS, const float* __restrict__ bbr,
    float* __restrict__ craw)
{
    __shared__ u16 smem[2][16384];
    const int tid = threadIdx.x, wave = tid >> 6, lane = tid & 63;
    const int p = blockIdx.y >> 5;              // 32 row-blocks per bucket
    const int rb0 = (blockIdx.y & 31) * 128;
    const int cntp = cnt[p];
    if (rb0 >= cntp) return;
    const int c0 = blockIdx.x * 128;
    const int pbase = p * 256;
    const int srl = lane >> 2;
    const int ssl = ((lane & 3) ^ ((lane >> 3) & 3)) * 8;
    const int frl = lane & 15, kh = lane >> 4;
    const int sw  = (kh ^ ((frl >> 1) & 3)) * 8;
    const int arow0 = (wave >> 1) * 64, bcol0 = (wave & 1) * 64;
    const int w32 = wave * 32;
    // per-lane staging tokens (perm zero-filled => token 0 for padded rows)
    const int tok0 = perm[p * CAP + rb0 + w32 + srl];
    const int tok1 = perm[p * CAP + rb0 + w32 + 16 + srl];

    f32x4 acc[4][4] = {};

    auto STAGE = [&](int buf, int k0) {
        u16* base = &smem[buf][0];
        u16* As_h = base;        u16* As_l = base + 4096;
        u16* Bs_h = base + 8192; u16* Bs_l = base + 12288;
        const long ga0 = (long)tok0 * Kc + pbase + k0 + ssl;
        const long ga1 = (long)tok1 * Kc + pbase + k0 + ssl;
        gld16(&As_h[w32 * 32],        hph + ga0);
        gld16(&As_h[(w32 + 16) * 32], hph + ga1);
        gld16(&As_l[w32 * 32],        hpl + ga0);
        gld16(&As_l[(w32 + 16) * 32], hpl + ga1);
        const long gb0 = (long)(c0 + w32 + srl) * Kc + pbase + k0 + ssl;
        gld16(&Bs_h[w32 * 32],        Wbth + gb0);
        gld16(&Bs_h[(w32 + 16) * 32], Wbth + gb0 + 16L * Kc);
        gld16(&Bs_l[w32 * 32],        Wbtl + gb0);
        gld16(&Bs_l[(w32 + 16) * 32], Wbtl + gb0 + 16L * Kc);
    };
    auto COMPUTE = [&](int buf) {
        u16* base = &smem[buf][0];
        u16* As_h = base;        u16* As_l = base + 4096;
        u16* Bs_h = base + 8192; u16* Bs_l = base + 12288;
        bf16x8 ah[4], al[4];
#pragma unroll
        for (int f = 0; f < 4; ++f) {
            int ao = (arow0 + f * 16 + frl) * 32 + sw;
            ah[f] = *(const bf16x8*)&As_h[ao];
            al[f] = *(const bf16x8*)&As_l[ao];
        }
#pragma unroll
        for (int j = 0; j < 4; ++j) {
            int bo = (bcol0 + j * 16 + frl) * 32 + sw;
            bf16x8 bh = *(const bf16x8*)&Bs_h[bo];
            bf16x8 bl = *(const bf16x8*)&Bs_l[bo];
#pragma unroll
            for (int i = 0; i < 4; ++i) {
                acc[i][j] = __builtin_amdgcn_mfma_f32_16x16x32_bf16(ah[i], bh, acc[i][j], 0, 0, 0);
                acc[i][j] = __builtin_amdgcn_mfma_f32_16x16x32_bf16(ah[i], bl, acc[i][j], 0, 0, 0);
                acc[i][j] = __builtin_amdgcn_mfma_f32_16x16x32_bf16(al[i], bh, acc[i][j], 0, 0, 0);
            }
        }
    };

    STAGE(0, 0);
#pragma unroll 1
    for (int t = 0; t < 8; t += 2) {        // K=256 -> 8 tiles
        STAGE(1, (t + 1) * 32);
        asm volatile("s_waitcnt vmcnt(8)" ::: "memory");
        __builtin_amdgcn_sched_barrier(0);
        __builtin_amdgcn_s_barrier();
        __builtin_amdgcn_sched_barrier(0);
        COMPUTE(0);
        __builtin_amdgcn_sched_barrier(0);
        __builtin_amdgcn_s_barrier();
        __builtin_amdgcn_sched_barrier(0);
        if (t + 2 < 8) {
            STAGE(0, (t + 2) * 32);
            asm volatile("s_waitcnt vmcnt(8)" ::: "memory");
        } else {
            asm volatile("s_waitcnt vmcnt(0)" ::: "memory");
        }
        __builtin_amdgcn_sched_barrier(0);
        __builtin_amdgcn_s_barrier();
        __builtin_amdgcn_sched_barrier(0);
        COMPUTE(1);
        __builtin_amdgcn_sched_barrier(0);
        __builtin_amdgcn_s_barrier();
        __builtin_amdgcn_sched_barrier(0);
    }

#pragma unroll
    for (int i = 0; i < 4; ++i)
#pragma unroll
        for (int reg = 0; reg < 4; ++reg) {
            const int gr = rb0 + arow0 + i * 16 + kh * 4 + reg;
            if (gr < cntp) {
                const int tokr = perm[p * CAP + gr];
                const float w = 1.f / rwS[(long)tokr * Pp + p];
#pragma unroll
                for (int j = 0; j < 4; ++j) {
                    const int c = c0 + bcol0 + j * 16 + frl;
                    craw[(long)tokr * Dd + c] = acc[i][j][reg] * w + bbr[p * 1024 + c];
                }
            }
        }
}

// ---------------- logits + softmax / hard-argmax ----------------
__global__ void logits_k(const float* __restrict__ h, const float* __restrict__ W2r,
                         const float* __restrict__ b2r, const float* __restrict__ gum,
                         float* __restrict__ rwA, int* __restrict__ pstar, int hard)
{
    __shared__ float hs[Mm];
    __shared__ float lg[16];
    int n = blockIdx.x;
    for (int i = threadIdx.x; i < Mm; i += 64) hs[i] = h[(long)n * Mm + i];
    __syncthreads();
    if (threadIdx.x < Pp) {
        int p = threadIdx.x;
        float acc = b2r[p];
        for (int m = 0; m < Mm; ++m) acc += hs[m] * W2r[m * Pp + p];
        lg[p] = acc + gum[(long)n * Pp + p];
    }
    __syncthreads();
    if (threadIdx.x == 0) {
        float mx = lg[0]; int am = 0;
#pragma unroll
        for (int p = 1; p < Pp; ++p) if (lg[p] > mx) { mx = lg[p]; am = p; }
        if (hard) {
            pstar[n] = am;
        } else {
            float e[Pp]; float ssum = 0.f;
#pragma unroll
            for (int p = 0; p < Pp; ++p) { e[p] = expf(lg[p] - mx); ssum += e[p]; }
#pragma unroll
            for (int p = 0; p < Pp; ++p) rwA[(long)n * Pp + p] = e[p] / ssum;
        }
    }
}

// ---------------- mod-phase RMS norm (group = d % 7) ----------------
template<int INSPLIT, int OUTSPLIT>
__global__ void norm_k(const float* __restrict__ in,
                       const u16* __restrict__ inh, const u16* __restrict__ inl,
                       const float* __restrict__ add, const float* __restrict__ g,
                       float* __restrict__ outf, u16* __restrict__ oh, u16* __restrict__ ol)
{
    __shared__ float sb[256][8];
    __shared__ float dn[8];
    int n = blockIdx.x;
    int t = threadIdx.x;
    float v[4];
#pragma unroll
    for (int j = 0; j < 7; ++j) sb[t][j] = 0.f;
#pragma unroll
    for (int i = 0; i < 4; ++i) {
        int d = t + i * 256;
        long o = (long)n * Dd + d;
        float xv = INSPLIT ? (bf2f(inh[o]) + bf2f(inl[o])) : in[o];
        if (add) xv += add[o];
        v[i] = xv;
        sb[t][d % 7] += xv * xv;
    }
    __syncthreads();
    for (int st = 128; st >= 1; st >>= 1) {
        if (t < st) {
#pragma unroll
            for (int j = 0; j < 7; ++j) sb[t][j] += sb[t + st][j];
        }
        __syncthreads();
    }
    if (t < 7) {
        const float cnt = (t < 2) ? 147.f : 146.f;
        dn[t] = 1.f / sqrtf(sb[0][t] / cnt + EPSf);
    }
    __syncthreads();
#pragma unroll
    for (int i = 0; i < 4; ++i) {
        int d = t + i * 256;
        long o = (long)n * Dd + d;
        float ov = v[i] * dn[d % 7] * g[d];
        if (OUTSPLIT) { u16 h, l; split2(ov, h, l); oh[o] = h; ol[o] = l; }
        else outf[o] = ov;
    }
}

static inline int cdiv(long a, long b) { return (int)((a + b - 1) / b); }
static inline size_t al256(size_t b) { return (b + 255) & ~(size_t)255; }

extern "C" void kernel_launch(void* const* d_in, const int* in_sizes, int n_in,
                              void* d_out, int out_size, void* d_ws, size_t ws_size,
                              hipStream_t stream)
{
    const float* x    = (const float*)d_in[0];
    const float* gum  = (const float*)d_in[1];
    const float* mw   = (const float*)d_in[2];
    const float* W1   = (const float*)d_in[3];
    const float* b1   = (const float*)d_in[4];
    const float* th1  = (const float*)d_in[5];
    const float* W2   = (const float*)d_in[6];
    const float* b2   = (const float*)d_in[7];
    const float* th2  = (const float*)d_in[8];
    const float* Wa   = (const float*)d_in[9];
    const float* ba   = (const float*)d_in[10];
    const float* tha  = (const float*)d_in[11];
    const float* Wb   = (const float*)d_in[12];
    const float* bbv  = (const float*)d_in[13];
    const float* thb  = (const float*)d_in[14];
    const float* tW   = (const float*)d_in[15];
    const float* tb   = (const float*)d_in[16];
    const float* tth  = (const float*)d_in[17];
    const float* gnorm = (const float*)d_in[18];

    char* cur = (char*)d_ws;
    auto alloc = [&](size_t bytes) -> void* { void* r = cur; cur += al256(bytes); return r; };

    void* region = alloc((size_t)Nn * Dd * 4);   // craw f32 == hbuf f32 == xm split
    float* zx   = (float*)alloc((size_t)Nn * Mm * 4);
    float* rwS  = (float*)alloc((size_t)Nn * Pp * 4);
    u16* colh = (u16*)alloc((size_t)Nn * Dd * 2);
    u16* coll = (u16*)alloc((size_t)Nn * Dd * 2);
    u16* hph  = (u16*)alloc((size_t)Nn * Kc * 2);
    u16* hpl  = (u16*)alloc((size_t)Nn * Kc * 2);
    u16* W1th = (u16*)alloc(256 * 2048 * 2);
    u16* W1tl = (u16*)alloc(256 * 2048 * 2);
    u16* Wath = (u16*)alloc((size_t)Kc * 1024 * 2);
    u16* Watl = (u16*)alloc((size_t)Kc * 1024 * 2);
    u16* Wbth = (u16*)alloc((size_t)1024 * Kc * 2);
    u16* Wbtl = (u16*)alloc((size_t)1024 * Kc * 2);
    u16* zxah  = (u16*)alloc((size_t)Nn * Kc * 2);
    u16* zxal  = (u16*)alloc((size_t)Nn * Kc * 2);
    u16* tWtTh = (u16*)alloc((size_t)1024 * 1024 * 2);
    u16* tWtTl = (u16*)alloc((size_t)1024 * 1024 * 2);
    u16* Wfath = (u16*)alloc((size_t)Kc * 1024 * 2);
    u16* Wfatl = (u16*)alloc((size_t)Kc * 1024 * 2);
    float* W2r  = (float*)alloc(256 * 9 * 4);
    float* b1r  = (float*)alloc(256 * 4);
    float* b2r  = (float*)alloc(64);
    float* bac  = (float*)alloc(Kc * 4);
    float* bac2 = (float*)alloc(Kc * 4);
    float* bbr  = (float*)alloc(Pp * 1024 * 4);
    float* tbr  = (float*)alloc(1024 * 4);
    int* pstar = (int*)alloc(Nn * 4);
    int* perm  = (int*)alloc((size_t)Pp * CAP * 4);
    int* cnt   = (int*)alloc(Pp * 4);
    if ((size_t)(cur - (char*)d_ws) > ws_size) return;   // fail loudly

    float* hbuf = (float*)region;
    float* craw = (float*)region;
    u16* xmh = (u16*)region;                 // xm dead before hbuf first write
    u16* xml = xmh + (size_t)Nn * Dd;
    float* out0 = (float*)d_out;
    float* out1 = out0 + (long)Nn * Dd;

    // ---- prep ----
    splitW1_k<<<2048, 256, 0, stream>>>(W1, th1, W1th, W1tl);
    splitWa_k<<<cdiv((long)Kc * 1024, 256), 256, 0, stream>>>(Wa, tha, Wath, Watl);
    splitWb_k<<<cdiv((long)1024 * Kc, 256), 256, 0, stream>>>(Wb, thb, Wbth, Wbtl);
    rotcopy_k<<<cdiv(256L * 9, 256), 256, 0, stream>>>(W2, W2r, 256, 9, th2, 1);
    rotcopy_k<<<1, 256, 0, stream>>>(b1, b1r, 1, 256, th1, 1);
    rotcopy_k<<<1, 256, 0, stream>>>(b2, b2r, 1, 9, th2, 1);
    rotcopy_k<<<cdiv((long)Pp * Mm, 256), 256, 0, stream>>>(ba, bac, 1, 256, tha, 9);
    rotcopy_k<<<cdiv((long)Pp * 1024, 256), 256, 0, stream>>>(bbv, bbr, 1, 1024, thb, 9);
    rotcopy_k<<<cdiv(1024L, 256), 256, 0, stream>>>(tb, tbr, 1, 1024, tth, 1);
    splitTWT_k<<<4096, 256, 0, stream>>>(tW, tth, tWtTh, tWtTl);
    hipMemsetAsync(perm, 0, (size_t)Pp * CAP * 4, stream);
    hipMemsetAsync(cnt, 0, Pp * 4, stream);

    // Wfat[pm,e] = sum_d Wat[pm,d] * tWtT[e,d]
    mgemm<6><<<dim3(8, 18), 256, 0, stream>>>(
        Wath, Watl, 1024, tWtTh, tWtTl, 1024, 1024,
        nullptr, Wfath, Wfatl, 1024, nullptr, nullptr, nullptr, nullptr, nullptr);
    bac2_k<<<Kc, 256, 0, stream>>>(bac, tbr, Wath, Watl, bac2);

    mixer_k<<<Nn * Dd / 4 / 256, 256, 0, stream>>>(x, mw, xmh, xml);
    // zx = xm @ W1_top + b1r  (skinny, 256 blocks)
    mgemmS<0><<<dim3(2, 128), 128, 0, stream>>>(
        xmh, xml, 1024, W1th, W1tl, 2048, 1024, zx, 256, nullptr, b1r);
    // zxa = xm @ Wat + bac2   (split out) — before tanh clobbers xm
    mgemm<6><<<dim3(18, 64), 256, 0, stream>>>(
        xmh, xml, 1024, Wath, Watl, 1024, 1024,
        nullptr, zxah, zxal, Kc, nullptr, nullptr, bac2, nullptr, nullptr);

    for (int t = 0; t < 3; ++t) {
        if (t == 0) {
            tanh_k<<<cdiv((long)Nn * Mm, 256), 256, 0, stream>>>(zx, hbuf, Nn * Mm);
        } else {
            mgemmS<1><<<dim3(2, 128), 128, 0, stream>>>(
                colh, coll, 1024, W1th + 1024, W1tl + 1024, 2048, 1024,
                hbuf, 256, zx, nullptr);
        }
        logits_k<<<Nn, 64, 0, stream>>>(hbuf, W2r, b2r, gum + (long)t * Nn * Pp,
                                        rwS, nullptr, 0);
        if (t == 0) {
            hp0_k<<<cdiv((long)Nn * Kc / 4, 256), 256, 0, stream>>>(zxah, zxal, rwS, hph, hpl);
        } else {
            // hp = (zxa + col @ Wfat) * rw
            mgemm<7><<<dim3(18, 64), 256, 0, stream>>>(
                colh, coll, 1024, Wfath, Wfatl, 1024, 1024,
                nullptr, hph, hpl, Kc, zxah, zxal, nullptr, rwS, nullptr);
        }
        // craw = hp @ Wbt + sum_p rw_p bbr_p
        mgemm<5><<<dim3(8, 64), 256, 0, stream>>>(
            hph, hpl, Kc, Wbth, Wbtl, Kc, Kc,
            craw, nullptr, nullptr, 1024, nullptr, nullptr, nullptr, rwS, bbr);
        norm_k<0, 1><<<Nn, 256, 0, stream>>>(craw, nullptr, nullptr, nullptr, gnorm,
                                             nullptr, colh, coll);
    }

    // ---- final hard routing (bucketed) ----
    mgemmS<1><<<dim3(2, 128), 128, 0, stream>>>(
        colh, coll, 1024, W1th + 1024, W1tl + 1024, 2048, 1024,
        hbuf, 256, zx, nullptr);
    logits_k<<<Nn, 64, 0, stream>>>(hbuf, W2r, b2r, gum + 3L * Nn * Pp,
                                    nullptr, pstar, 1);
    bucket_k<<<32, 256, 0, stream>>>(pstar, cnt, perm);
    // fc_raw[tok] = (hp[tok, p* slice] @ Wb_p*) / rwS[tok,p*] + bbr[p*]
    mgemm_fin<<<dim3(8, Pp * 32), 256, 0, stream>>>(
        hph, hpl, Wbth, Wbtl, perm, cnt, rwS, bbr, craw);
    // out0 = norm(x + fc_raw); out1 = norm(collapsed)
    norm_k<0, 0><<<Nn, 256, 0, stream>>>(craw, nullptr, nullptr, x, gnorm, out0, nullptr, nullptr);
    norm_k<1, 0><<<Nn, 256, 0, stream>>>(nullptr, colh, coll, nullptr, gnorm, out1, nullptr, nullptr);
}